// Round 8
// baseline (337.544 us; speedup 1.0000x reference)
//
#include <hip/hip_runtime.h>
#include <cstdint>
#include <cstddef>

typedef unsigned short u16;
typedef unsigned int u32;
typedef __bf16 bf16x8 __attribute__((ext_vector_type(8)));
typedef float f32x4 __attribute__((ext_vector_type(4)));

#define DEVI static __device__ __forceinline__

// round-to-nearest-even fp32 -> bf16
DEVI u16 f2bf(float f) {
  u32 u = __builtin_bit_cast(u32, f);
  u = (u + 0x7fffu + ((u >> 16) & 1u)) >> 16;
  return (u16)u;
}
DEVI float bf2f(u16 u) { return __builtin_bit_cast(float, (u32)u << 16); }

// async global->LDS, 16B per lane. HW writes lane i at (lane0 base) + i*16.
DEVI void gll16(const void* gsrc, const void* ldst) {
  __builtin_amdgcn_global_load_lds(
      (const __attribute__((address_space(1))) u32*)(uintptr_t)gsrc,
      (__attribute__((address_space(3))) u32*)(u32)(uintptr_t)ldst, 16, 0, 0);
}

DEVI float wredsum(float v) {
  v += __shfl_xor(v, 32); v += __shfl_xor(v, 16); v += __shfl_xor(v, 8);
  v += __shfl_xor(v, 4);  v += __shfl_xor(v, 2);  v += __shfl_xor(v, 1);
  return v;
}

// ---------------- transpose + cvt: fp32 [R][C] -> bf16 [C][R] ----------------
__global__ __launch_bounds__(256) void k_tcvt(const float* __restrict__ in, u16* __restrict__ out,
                                              int R, int C, long in_z, long out_z) {
  __shared__ float tile[32][33];
  const float* inp = in + (long)blockIdx.z * in_z;
  u16* outp = out + (long)blockIdx.z * out_z;
  int c0 = blockIdx.x * 32, r0 = blockIdx.y * 32;
  int tx = threadIdx.x & 31, ty = threadIdx.x >> 5;
#pragma unroll
  for (int i = 0; i < 4; ++i)
    tile[ty + i * 8][tx] = inp[(long)(r0 + ty + i * 8) * C + c0 + tx];
  __syncthreads();
#pragma unroll
  for (int i = 0; i < 4; ++i) {
    int cc = ty + i * 8;
    outp[(long)(c0 + cc) * R + r0 + tx] = f2bf(tile[tx][cc]);
  }
}

// ---------------- elementwise fp32 -> bf16 ----------------
__global__ __launch_bounds__(256) void k_cvt(const float* __restrict__ in, u16* __restrict__ out, int n4) {
  int i = blockIdx.x * 256 + threadIdx.x;
  if (i >= n4) return;
  float4 v = ((const float4*)in)[i];
  ushort4 o;
  o.x = f2bf(v.x); o.y = f2bf(v.y); o.z = f2bf(v.z); o.w = f2bf(v.w);
  ((ushort4*)out)[i] = o;
}

// ============ occupancy-first bf16 GEMM ============
// C = A[M][K]*Bt[N][K]^T (+bias). Tile 128x128, BK=32, 4 waves (2M x 2N),
// per-wave 64x64 (acc[4][4] = 64 regs). TOTAL regs targeted <= 128
// (launch_bounds(256,4)) => 4 waves/SIMD; LDS 32KB 2-buf => 4 blocks/CU
// => 16 resident waves/CU. Evidence (R1-R7): TF ~ resident waves (latency-
// bound regime); all prior variants were reg-capped to <=8 waves/CU.
// K-major LDS unit [g2:4][128 rows][16B]: gll16 staging and ds_read_b128 both
// conflict-free (R3/R6/R7: SQ_LDS_BANK_CONFLICT = 0).
// Loop (m97-pattern, prefetch-1, ONE __syncthreads per K-tile):
//   { STG(t+1)->buf[~t&1] (4 loads/thr); read 8 frags from buf[t&1];
//     16 MFMA; __syncthreads() }
// Safety: reads(t) of buf[t&1] complete before bar(t) (lgkmcnt before MFMA);
// STG(t+2) into buf[t&1] is issued only after bar(t+?) in iter t+1 -> no
// clobber. Residency: __syncthreads drains each wave's own vmcnt(0); joint
// barrier => all waves' staging of (t+1) complete before t+1 reads. No raw
// barriers, no counted vmcnt.
// Split-K via z: output at base + z*pofs. EPI: 0=f32, 1=bf16(+bias), 2=GELU->bf16
template <int EPI>
__global__ __launch_bounds__(256, 4) void k_gemmC(const u16* __restrict__ A, const u16* __restrict__ Bt,
                                                  const float* __restrict__ bias, void* __restrict__ Cout,
                                                  long pofs, int M, int N, int K, int Kc) {
  __shared__ __align__(16) u16 lds[16384];  // 32 KB: 2 buf x {A 8KB + B 8KB}
  char* Lc = (char*)&lds[0];
  const int tid = threadIdx.x;
  const int lane = tid & 63, wid = tid >> 6;
  const int wr = wid >> 1, wc = wid & 1;   // 2 M-waves x 2 N-waves
  const int g = lane >> 4, r16 = lane & 15;

  // bijective XCD swizzle (grid % 8 == 0 for all launches)
  const int gx = N >> 7, gy = M >> 7;
  const int cpx = (int)gridDim.x >> 3;
  int bb = (int)blockIdx.x;
  int id = (bb & 7) * cpx + (bb >> 3);
  const int gxy = gx * gy;
  const int bz = id / gxy;
  int rr2 = id - bz * gxy;
  const int by = rr2 / gx;
  const int bx = rr2 - by * gx;
  const long row0 = (long)by * 128;
  const long col0 = (long)bx * 128;
  const long kbeg = (long)bz * Kc;
  const int nk = Kc >> 5;  // BK=32 K-tiles (nk >= 2)

  const size_t KB = (size_t)K * 2;  // global row stride in bytes
  const char* Ab = (const char*)A + (size_t)row0 * KB + (size_t)kbeg * 2;
  const char* Bb = (const char*)Bt + (size_t)col0 * KB + (size_t)kbeg * 2;

  // stage one K-tile {A 8KB, B 8KB} into buffer `off`: 4 gll16/thread (256 thr)
#define STG1(t_, off)                                                            \
  do {                                                                           \
    const char* ga_ = Ab + (size_t)(t_) * 64;                                    \
    const char* gb_ = Bb + (size_t)(t_) * 64;                                    \
    _Pragma("unroll") for (int i_ = 0; i_ < 2; ++i_) {                           \
      int gi_ = i_ * 256 + tid;                                                  \
      int g2_ = gi_ >> 7, row_ = gi_ & 127;                                      \
      gll16(ga_ + (size_t)row_ * KB + g2_ * 16, Lc + (off) + gi_ * 16);          \
      gll16(gb_ + (size_t)row_ * KB + g2_ * 16, Lc + (off) + 8192 + gi_ * 16);   \
    }                                                                            \
  } while (0)

  f32x4 acc[4][4];
#pragma unroll
  for (int i = 0; i < 4; ++i)
#pragma unroll
    for (int j = 0; j < 4; ++j) acc[i][j] = {0.f, 0.f, 0.f, 0.f};

  // prologue: tile 0 -> buf0
  STG1(0, 0);
  __syncthreads();

  // per-lane ds_read bases (byte, within buffer)
  const int vA = g * 2048 + (wr * 64 + r16) * 16;         // + m*256
  const int vB = 8192 + g * 2048 + (wc * 64 + r16) * 16;  // + n*256

  for (int t = 0; t < nk; ++t) {
    const int buf = (t & 1) * 16384;
    if (t + 1 < nk) STG1(t + 1, 16384 - buf);
    const char* S = Lc + buf;
    bf16x8 aF[4], bF[4];
#pragma unroll
    for (int m = 0; m < 4; ++m) aF[m] = *(const bf16x8*)(S + vA + m * 256);
#pragma unroll
    for (int n = 0; n < 4; ++n) bF[n] = *(const bf16x8*)(S + vB + n * 256);
    __builtin_amdgcn_s_setprio(1);
#pragma unroll
    for (int m = 0; m < 4; ++m)
#pragma unroll
      for (int n = 0; n < 4; ++n)
        acc[m][n] = __builtin_amdgcn_mfma_f32_16x16x32_bf16(aF[m], bF[n], acc[m][n], 0, 0, 0);
    __builtin_amdgcn_s_setprio(0);
    __syncthreads();
  }
#undef STG1

  // epilogue: C/D mapping col=lane&15, row=(lane>>4)*4+j
  float* outf = (float*)Cout + (long)bz * pofs;
  u16* outh = (u16*)Cout + (long)bz * pofs;
#pragma unroll
  for (int n = 0; n < 4; ++n) {
    long col = col0 + wc * 64 + n * 16 + r16;
    float bv = bias ? bias[col] : 0.f;
#pragma unroll
    for (int m = 0; m < 4; ++m) {
      long rowb = row0 + wr * 64 + m * 16 + g * 4;
#pragma unroll
      for (int j = 0; j < 4; ++j) {
        float v = acc[m][n][j] + bv;
        size_t off = (size_t)(rowb + j) * N + col;
        if (EPI == 0) {
          outf[off] = v;
        } else if (EPI == 1) {
          outh[off] = f2bf(v);
        } else {
          float gl = 0.5f * v * (1.f + erff(v * 0.70710678118f));
          outh[off] = f2bf(gl);
        }
      }
    }
  }
}

// ---------------- build V^T: qkvb[token][2048+h*64+p] -> vt[(b,h)][p][s] ----------------
__global__ __launch_bounds__(256) void k_build_vt(const u16* __restrict__ qkvb, u16* __restrict__ vt) {
  __shared__ u16 tile[32][33];
  int z = blockIdx.z, b = z >> 4, h = z & 15;
  int p0 = blockIdx.x * 32, s0 = blockIdx.y * 32;
  int tx = threadIdx.x & 31, ty = threadIdx.x >> 5;
#pragma unroll
  for (int i = 0; i < 4; ++i) {
    int s = s0 + ty + i * 8;
    tile[ty + i * 8][tx] = qkvb[(size_t)(b * 512 + s) * 3072 + 2048 + h * 64 + p0 + tx];
  }
  __syncthreads();
#pragma unroll
  for (int i = 0; i < 4; ++i) {
    int p = ty + i * 8;
    vt[((size_t)z * 64 + p0 + p) * 512 + s0 + tx] = tile[tx][p];
  }
}

// ---------------- fused flash attention ----------------
__global__ __launch_bounds__(256) void k_attn(const u16* __restrict__ qkvb, const u16* __restrict__ vt,
                                              u16* __restrict__ ctxb) {
  __shared__ __align__(16) u16 Qs[64 * 64];
  __shared__ __align__(16) u16 Ks[64 * 64];
  __shared__ __align__(16) u16 Vts[64 * 64];
  __shared__ __align__(16) u16 Ps[4 * 16 * 64];
  const int tid = threadIdx.x, lane = tid & 63, wid = tid >> 6;
  const int g = lane >> 4, r16 = lane & 15;
  const int z = blockIdx.y, b = z >> 4, h = z & 15;
  const int qt = blockIdx.x;
  const float CF = 0.125f * 1.44269504089f;

#pragma unroll
  for (int it = 0; it < 2; ++it) {
    int q = it * 4096 + tid * 16;
    int row = q >> 7, colb = q & 127;
    int scol = colb ^ ((row & 7) << 4);
    gll16((const char*)qkvb + ((size_t)(b * 512 + qt * 64 + row) * 3072 + h * 64) * 2 + scol,
          (const char*)Qs + it * 4096 + wid * 1024);
  }
  __syncthreads();
  bf16x8 aq[2];
  {
    int rowl = wid * 16 + r16;
#pragma unroll
    for (int kk = 0; kk < 2; ++kk)
      aq[kk] = *(const bf16x8*)(Qs + rowl * 64 + ((kk * 32 + g * 8) ^ ((rowl & 7) << 3)));
  }

  f32x4 o[4];
#pragma unroll
  for (int pi = 0; pi < 4; ++pi) o[pi] = {0.f, 0.f, 0.f, 0.f};
  float m4[4], l4[4];
#pragma unroll
  for (int j = 0; j < 4; ++j) { m4[j] = -1e30f; l4[j] = 0.f; }

  for (int kt = 0; kt < 8; ++kt) {
#pragma unroll
    for (int it = 0; it < 2; ++it) {
      int q = it * 4096 + tid * 16;
      int row = q >> 7, colb = q & 127;
      int scol = colb ^ ((row & 7) << 4);
      gll16((const char*)qkvb + ((size_t)(b * 512 + kt * 64 + row) * 3072 + 1024 + h * 64) * 2 + scol,
            (const char*)Ks + it * 4096 + wid * 1024);
      gll16((const char*)vt + ((size_t)(z * 64 + row) * 512 + kt * 64) * 2 + scol,
            (const char*)Vts + it * 4096 + wid * 1024);
    }
    __syncthreads();

    f32x4 s[4];
#pragma unroll
    for (int nj = 0; nj < 4; ++nj) s[nj] = {0.f, 0.f, 0.f, 0.f};
#pragma unroll
    for (int kk = 0; kk < 2; ++kk) {
#pragma unroll
      for (int nj = 0; nj < 4; ++nj) {
        int rowk = nj * 16 + r16;
        bf16x8 bk = *(const bf16x8*)(Ks + rowk * 64 + ((kk * 32 + g * 8) ^ ((rowk & 7) << 3)));
        s[nj] = __builtin_amdgcn_mfma_f32_16x16x32_bf16(aq[kk], bk, s[nj], 0, 0, 0);
      }
    }

    float scale[4];
#pragma unroll
    for (int j = 0; j < 4; ++j) {
      float pm = fmaxf(fmaxf(s[0][j], s[1][j]), fmaxf(s[2][j], s[3][j]));
      pm = fmaxf(pm, __shfl_xor(pm, 1));
      pm = fmaxf(pm, __shfl_xor(pm, 2));
      pm = fmaxf(pm, __shfl_xor(pm, 4));
      pm = fmaxf(pm, __shfl_xor(pm, 8));
      float mn = fmaxf(m4[j], pm);
      scale[j] = exp2f((m4[j] - mn) * CF);
      m4[j] = mn;
      int rowp = g * 4 + j;
      u16* pbase = Ps + wid * 1024 + rowp * 64;
      int sw = (rowp & 7) << 3;
      float ps = 0.f;
#pragma unroll
      for (int nj = 0; nj < 4; ++nj) {
        float p = exp2f((s[nj][j] - mn) * CF);
        ps += p;
        pbase[(nj * 16 + r16) ^ sw] = f2bf(p);
      }
      ps += __shfl_xor(ps, 1); ps += __shfl_xor(ps, 2);
      ps += __shfl_xor(ps, 4); ps += __shfl_xor(ps, 8);
      l4[j] = l4[j] * scale[j] + ps;
    }
#pragma unroll
    for (int pi = 0; pi < 4; ++pi)
#pragma unroll
      for (int j = 0; j < 4; ++j) o[pi][j] *= scale[j];

    asm volatile("s_waitcnt lgkmcnt(0)" ::: "memory");

#pragma unroll
    for (int kk = 0; kk < 2; ++kk) {
      bf16x8 ap = *(const bf16x8*)(Ps + wid * 1024 + r16 * 64 + ((kk * 32 + g * 8) ^ ((r16 & 7) << 3)));
#pragma unroll
      for (int pi = 0; pi < 4; ++pi) {
        int rowv = pi * 16 + r16;
        bf16x8 bv = *(const bf16x8*)(Vts + rowv * 64 + ((kk * 32 + g * 8) ^ ((rowv & 7) << 3)));
        o[pi] = __builtin_amdgcn_mfma_f32_16x16x32_bf16(ap, bv, o[pi], 0, 0, 0);
      }
    }
    __syncthreads();
  }

#pragma unroll
  for (int j = 0; j < 4; ++j) {
    float inv = 1.f / l4[j];
    int token = b * 512 + qt * 64 + wid * 16 + g * 4 + j;
#pragma unroll
    for (int pi = 0; pi < 4; ++pi)
      ctxb[(size_t)token * 1024 + h * 64 + pi * 16 + r16] = f2bf(o[pi][j] * inv);
  }
}

// ---------------- fused (4 bf16 partials) + bias + residual + LayerNorm ----------------
__global__ __launch_bounds__(256) void k_ln4(const u16* __restrict__ p, long pofs,
                                             const float* __restrict__ res, const float* __restrict__ bvec,
                                             const float* __restrict__ gamma, const float* __restrict__ beta,
                                             float* __restrict__ outf, u16* __restrict__ outb) {
  __shared__ float sb[8];
  int row = blockIdx.x, t = threadIdx.x, lane = t & 63, wid = t >> 6;
  const size_t rb = (size_t)row * 1024 + t * 4;
  float4 rv = *(const float4*)(res + rb);
  float4 bb = *(const float4*)(bvec + t * 4);
  float v[4] = {rv.x + bb.x, rv.y + bb.y, rv.z + bb.z, rv.w + bb.w};
#pragma unroll
  for (int z = 0; z < 4; ++z) {
    ushort4 u = *(const ushort4*)(p + (size_t)z * pofs + rb);
    v[0] += bf2f(u.x); v[1] += bf2f(u.y); v[2] += bf2f(u.z); v[3] += bf2f(u.w);
  }
  float s = v[0] + v[1] + v[2] + v[3];
  s = wredsum(s);
  if (lane == 0) sb[wid] = s;
  __syncthreads();
  float mu = (sb[0] + sb[1] + sb[2] + sb[3]) * (1.f / 1024.f);
  float q = 0.f;
#pragma unroll
  for (int i = 0; i < 4; ++i) { float d = v[i] - mu; q += d * d; }
  q = wredsum(q);
  if (lane == 0) sb[4 + wid] = q;
  __syncthreads();
  float rstd = rsqrtf((sb[4] + sb[5] + sb[6] + sb[7]) * (1.f / 1024.f) + 1e-5f);
  float4 gv = *(const float4*)(gamma + t * 4);
  float4 bt = *(const float4*)(beta + t * 4);
  float ov[4];
  ov[0] = (v[0] - mu) * rstd * gv.x + bt.x;
  ov[1] = (v[1] - mu) * rstd * gv.y + bt.y;
  ov[2] = (v[2] - mu) * rstd * gv.z + bt.z;
  ov[3] = (v[3] - mu) * rstd * gv.w + bt.w;
  *(float4*)(outf + rb) = {ov[0], ov[1], ov[2], ov[3]};
  if (outb) {
    ushort4 ob = {f2bf(ov[0]), f2bf(ov[1]), f2bf(ov[2]), f2bf(ov[3])};
    *(ushort4*)(outb + rb) = ob;
  }
}

// ---------------- orchestration ----------------
// Workspace map (MB), time-multiplexed (same as R6/R7):
//   [0,6) wqkvb | [6,8) woutb | [8,16) wffn1b | [16,24) free | [24,32) xb/ctxb/r1b
//   [32,56) qkvb -> qp0..2 -> hb | [56,64) vt -> qp3 -> hb | [64,72) free
//   [72,80) wffn2b.  qp0..3 @ [32,64) stride 8MB; pp0..3 @ [0,32) stride 8MB.
//   r1 fp32 in d_out. Peak 80 MB.
extern "C" void kernel_launch(void* const* d_in, const int* in_sizes, int n_in,
                              void* d_out, int out_size, void* d_ws, size_t ws_size,
                              hipStream_t stream) {
  const float* x      = (const float*)d_in[0];
  const float* w_qkv  = (const float*)d_in[1];
  const float* b_qkv  = (const float*)d_in[2];
  const float* w_out  = (const float*)d_in[3];
  const float* b_out  = (const float*)d_in[4];
  const float* ln1s   = (const float*)d_in[5];
  const float* ln1b   = (const float*)d_in[6];
  const float* w_ffn1 = (const float*)d_in[7];
  const float* b_ffn1 = (const float*)d_in[8];
  const float* w_ffn2 = (const float*)d_in[9];
  const float* b_ffn2 = (const float*)d_in[10];
  const float* ln2s   = (const float*)d_in[11];
  const float* ln2b   = (const float*)d_in[12];

  char* ws = (char*)d_ws;
  const size_t MB = 1024 * 1024;
  u16* wqkvb   = (u16*)(ws + 0 * MB);
  u16* woutb   = (u16*)(ws + 6 * MB);
  u16* wffn1b  = (u16*)(ws + 8 * MB);
  u16* wffn2b  = (u16*)(ws + 72 * MB);
  u16* xb      = (u16*)(ws + 24 * MB);
  u16* ctxb    = xb;
  u16* r1b     = xb;
  u16* qkvb    = (u16*)(ws + 32 * MB);
  u16* vt      = (u16*)(ws + 56 * MB);
  u16* qp      = (u16*)(ws + 32 * MB);   // 4 bf16 partials, stride 8MB
  u16* hb      = (u16*)(ws + 32 * MB);
  u16* pp      = (u16*)(ws + 0 * MB);    // 4 bf16 partials, stride 8MB
  float* r1    = (float*)d_out;
  float* outp  = (float*)d_out;
  const long PSTRIDE = 4096L * 1024L;    // elements per bf16 partial (8MB)

  // pack weights (transpose to [N][K] bf16)
  k_tcvt<<<dim3(32, 32, 3), 256, 0, stream>>>(w_qkv, wqkvb, 1024, 1024, 1024 * 1024, 1024 * 1024);
  k_tcvt<<<dim3(32, 32, 1), 256, 0, stream>>>(w_out, woutb, 1024, 1024, 0, 0);
  k_tcvt<<<dim3(128, 32, 1), 256, 0, stream>>>(w_ffn1, wffn1b, 1024, 4096, 0, 0);
  k_tcvt<<<dim3(32, 128, 1), 256, 0, stream>>>(w_ffn2, wffn2b, 4096, 1024, 0, 0);
  k_cvt<<<4096, 256, 0, stream>>>(x, xb, 1048576);

  // qkv = x @ w_qkv + b_qkv  (bf16 out): grid 24x32 = 768 blocks, nk=32
  k_gemmC<1><<<dim3(24 * 32), 256, 0, stream>>>(xb, wqkvb, b_qkv, qkvb, 0, 4096, 3072, 1024, 1024);
  k_build_vt<<<dim3(2, 16, 128), 256, 0, stream>>>(qkvb, vt);
  k_attn<<<dim3(8, 128), 256, 0, stream>>>(qkvb, vt, ctxb);

  // attn_out partials = ctx @ w_out (split-K=4, bf16 partials qp0..3, 1024 blocks, nk=8)
  k_gemmC<1><<<dim3(8 * 32 * 4), 256, 0, stream>>>(ctxb, woutb, nullptr, qp, PSTRIDE,
                                                   4096, 1024, 1024, 256);
  // r1 = LN(x + sum(qp) + b_out) -> fp32 (d_out) + bf16
  k_ln4<<<4096, 256, 0, stream>>>(qp, PSTRIDE, x, b_out, ln1s, ln1b, r1, r1b);

  // h = gelu(r1 @ w_ffn1 + b_ffn1): grid 32x32 = 1024 blocks, nk=32
  k_gemmC<2><<<dim3(32 * 32), 256, 0, stream>>>(r1b, wffn1b, b_ffn1, hb, 0, 4096, 4096, 1024, 1024);

  // ffn2 partials = h @ w_ffn2 (split-K=4, bf16 partials pp0..3, 1024 blocks, nk=32)
  k_gemmC<1><<<dim3(8 * 32 * 4), 256, 0, stream>>>(hb, wffn2b, nullptr, pp, PSTRIDE,
                                                   4096, 1024, 4096, 1024);
  // out = LN(r1 + sum(pp) + b_ffn2)
  k_ln4<<<4096, 256, 0, stream>>>(pp, PSTRIDE, r1, b_ffn2, ln2s, ln2b, outp, (u16*)nullptr);
}

// Round 9
// 323.944 us; speedup vs baseline: 1.0420x; 1.0420x over previous
//
#include <hip/hip_runtime.h>
#include <cstdint>
#include <cstddef>

typedef unsigned short u16;
typedef unsigned int u32;
typedef __bf16 bf16x8 __attribute__((ext_vector_type(8)));
typedef float f32x4 __attribute__((ext_vector_type(4)));

#define DEVI static __device__ __forceinline__

// round-to-nearest-even fp32 -> bf16
DEVI u16 f2bf(float f) {
  u32 u = __builtin_bit_cast(u32, f);
  u = (u + 0x7fffu + ((u >> 16) & 1u)) >> 16;
  return (u16)u;
}
DEVI float bf2f(u16 u) { return __builtin_bit_cast(float, (u32)u << 16); }

// async global->LDS, 16B per lane. HW writes lane i at (lane0 base) + i*16.
DEVI void gll16(const void* gsrc, const void* ldst) {
  __builtin_amdgcn_global_load_lds(
      (const __attribute__((address_space(1))) u32*)(uintptr_t)gsrc,
      (__attribute__((address_space(3))) u32*)(u32)(uintptr_t)ldst, 16, 0, 0);
}

DEVI float wredsum(float v) {
  v += __shfl_xor(v, 32); v += __shfl_xor(v, 16); v += __shfl_xor(v, 8);
  v += __shfl_xor(v, 4);  v += __shfl_xor(v, 2);  v += __shfl_xor(v, 1);
  return v;
}

// raw s_barrier with compiler memory fences (no vmcnt drain)
DEVI void barx() {
  asm volatile("" ::: "memory");
  __builtin_amdgcn_s_barrier();
  asm volatile("" ::: "memory");
}

// ---------------- transpose + cvt: fp32 [R][C] -> bf16 [C][R] ----------------
__global__ __launch_bounds__(256) void k_tcvt(const float* __restrict__ in, u16* __restrict__ out,
                                              int R, int C, long in_z, long out_z) {
  __shared__ float tile[32][33];
  const float* inp = in + (long)blockIdx.z * in_z;
  u16* outp = out + (long)blockIdx.z * out_z;
  int c0 = blockIdx.x * 32, r0 = blockIdx.y * 32;
  int tx = threadIdx.x & 31, ty = threadIdx.x >> 5;
#pragma unroll
  for (int i = 0; i < 4; ++i)
    tile[ty + i * 8][tx] = inp[(long)(r0 + ty + i * 8) * C + c0 + tx];
  __syncthreads();
#pragma unroll
  for (int i = 0; i < 4; ++i) {
    int cc = ty + i * 8;
    outp[(long)(c0 + cc) * R + r0 + tx] = f2bf(tile[tx][cc]);
  }
}

// ---------------- elementwise fp32 -> bf16 ----------------
__global__ __launch_bounds__(256) void k_cvt(const float* __restrict__ in, u16* __restrict__ out, int n4) {
  int i = blockIdx.x * 256 + threadIdx.x;
  if (i >= n4) return;
  float4 v = ((const float4*)in)[i];
  ushort4 o;
  o.x = f2bf(v.x); o.y = f2bf(v.y); o.z = f2bf(v.z); o.w = f2bf(v.w);
  ((ushort4*)out)[i] = o;
}

// ============ intensity-first ring-3 bf16 GEMM ============
// C = A[M][K]*Bt[N][K]^T (+bias). Tile 256x128 (best FLOP/staged-byte with a
// working schedule = R3), BK=32, 8 waves (4M x 2N), per-wave 64x64 (acc 64
// regs). LDS = ring of 3 slots x {A 16KB + B 8KB} = 72KB -> 2 blocks/CU;
// __launch_bounds__(512,4) caps regs at 128 so both blocks stay resident
// (16 waves/CU of cross-block overlap). K-major granule layout
// [g2:4][rows][16B]: staging and ds_read_b128 both conflict-free (R3/R6-R8:
// SQ_LDS_BANK_CONFLICT = 0).
// Per K-tile ONE phase, prefetch distance 2, counted vmcnt BEFORE the joint
// barrier (per-wave counter + cross-wave data — the R5 lesson):
//   { 8 ds_read from slot t%3 | STGD(t+2) -> slot (t+2)%3 | 16 MFMA |
//     vmcnt(3) [t==nk-2: vmcnt(0); t==nk-1: none] | s_barrier }
// Residency: each wave stages 3 loads/tile; after staging t+2 the wave has
// <=6 outstanding; vmcnt(3) retires t+1's 3 -> tile t+1 resident at barrier.
// Clobber: slot (t+2)%3 == slot (t-1)%3, whose readers' ds_reads completed
// (lgkmcnt before MFMA) before barrier(t-1), which precedes this staging.
// nk >= 3 required. Split-K via z: fp32 output at base + z*pofs.
// EPI: 0=f32, 1=bf16(+bias), 2=exact-GELU->bf16(+bias)
template <int EPI>
__global__ __launch_bounds__(512, 4) void k_gemmD(const u16* __restrict__ A, const u16* __restrict__ Bt,
                                                  const float* __restrict__ bias, void* __restrict__ Cout,
                                                  long pofs, int M, int N, int K, int Kc) {
  __shared__ __align__(16) u16 lds[36864];  // 72 KB = 3 x 24KB
  char* Lc = (char*)&lds[0];
  const int tid = threadIdx.x;
  const int lane = tid & 63, wid = tid >> 6;
  const int wr = wid >> 1, wc = wid & 1;   // 4 M-waves x 2 N-waves
  const int g = lane >> 4, r16 = lane & 15;

  // bijective XCD swizzle (grid % 8 == 0 for all launches)
  const int gx = N >> 7, gy = M >> 8;
  const int cpx = (int)gridDim.x >> 3;
  int bb = (int)blockIdx.x;
  int id = (bb & 7) * cpx + (bb >> 3);
  const int gxy = gx * gy;
  const int bz = id / gxy;
  int rr2 = id - bz * gxy;
  const int by = rr2 / gx;
  const int bx = rr2 - by * gx;
  const long row0 = (long)by * 256;
  const long col0 = (long)bx * 128;
  const long kbeg = (long)bz * Kc;
  const int nk = Kc >> 5;  // BK=32 K-tiles (nk >= 3)

  const size_t KB = (size_t)K * 2;  // global row stride in bytes
  const char* Ab = (const char*)A + (size_t)row0 * KB + (size_t)kbeg * 2;
  const char* Bb = (const char*)Bt + (size_t)col0 * KB + (size_t)kbeg * 2;

  // stage one K-tile {A 16KB [g2:4][256][16B], B 8KB [g2:4][128][16B]} into
  // slot `so` (byte offset): 3 gll16/thread (512 thr)
#define STGD(t_, so)                                                             \
  do {                                                                           \
    const char* ga_ = Ab + (size_t)(t_) * 64;                                    \
    const char* gb_ = Bb + (size_t)(t_) * 64;                                    \
    _Pragma("unroll") for (int i_ = 0; i_ < 2; ++i_) {                           \
      int gi_ = i_ * 512 + tid;                                                  \
      gll16(ga_ + (size_t)(gi_ & 255) * KB + (gi_ >> 8) * 16,                    \
            Lc + (so) + gi_ * 16);                                               \
    }                                                                            \
    gll16(gb_ + (size_t)(tid & 127) * KB + (tid >> 7) * 16,                      \
          Lc + (so) + 16384 + tid * 16);                                         \
  } while (0)

  f32x4 acc[4][4];
#pragma unroll
  for (int i = 0; i < 4; ++i)
#pragma unroll
    for (int j = 0; j < 4; ++j) acc[i][j] = {0.f, 0.f, 0.f, 0.f};

  // prologue: tiles 0,1 -> slots 0,1 (6 loads/thread); wait tile0 -> vmcnt(3)
  STGD(0, 0);
  STGD(1, 24576);
  asm volatile("s_waitcnt vmcnt(3)" ::: "memory");
  barx();

  // per-lane ds_read bases (byte, within slot)
  const int vA = g * 4096 + (wr * 64 + r16) * 16;          // + m*256
  const int vB = 16384 + g * 2048 + (wc * 64 + r16) * 16;  // + n*256

  int sl = 0, sl2 = 2;  // t%3, (t+2)%3
  for (int t = 0; t < nk; ++t) {
    const char* S = Lc + sl * 24576;
    bf16x8 aF[4], bF[4];
#pragma unroll
    for (int m = 0; m < 4; ++m) aF[m] = *(const bf16x8*)(S + vA + m * 256);
#pragma unroll
    for (int n = 0; n < 4; ++n) bF[n] = *(const bf16x8*)(S + vB + n * 256);
    if (t + 2 < nk) STGD(t + 2, sl2 * 24576);
    __builtin_amdgcn_s_setprio(1);
#pragma unroll
    for (int m = 0; m < 4; ++m)
#pragma unroll
      for (int n = 0; n < 4; ++n)
        acc[m][n] = __builtin_amdgcn_mfma_f32_16x16x32_bf16(aF[m], bF[n], acc[m][n], 0, 0, 0);
    __builtin_amdgcn_s_setprio(0);
    if (t < nk - 2) {
      asm volatile("s_waitcnt vmcnt(3)" ::: "memory");  // tile t+1 resident
    } else if (t == nk - 2) {
      asm volatile("s_waitcnt vmcnt(0)" ::: "memory");
    }
    barx();
    sl = (sl == 2) ? 0 : sl + 1;
    sl2 = (sl2 == 2) ? 0 : sl2 + 1;
  }
#undef STGD

  // epilogue: C/D mapping col=lane&15, row=(lane>>4)*4+j (verified R1..R8)
  float* outf = (float*)Cout + (long)bz * pofs;
  u16* outh = (u16*)Cout + (long)bz * pofs;
#pragma unroll
  for (int n = 0; n < 4; ++n) {
    long col = col0 + wc * 64 + n * 16 + r16;
    float bv = bias ? bias[col] : 0.f;
#pragma unroll
    for (int m = 0; m < 4; ++m) {
      long rowb = row0 + wr * 64 + m * 16 + g * 4;
#pragma unroll
      for (int j = 0; j < 4; ++j) {
        float v = acc[m][n][j] + bv;
        size_t off = (size_t)(rowb + j) * N + col;
        if (EPI == 0) {
          outf[off] = v;
        } else if (EPI == 1) {
          outh[off] = f2bf(v);
        } else {
          float gl = 0.5f * v * (1.f + erff(v * 0.70710678118f));
          outh[off] = f2bf(gl);
        }
      }
    }
  }
}

// ---------------- build V^T: qkvb[token][2048+h*64+p] -> vt[(b,h)][p][s] ----------------
__global__ __launch_bounds__(256) void k_build_vt(const u16* __restrict__ qkvb, u16* __restrict__ vt) {
  __shared__ u16 tile[32][33];
  int z = blockIdx.z, b = z >> 4, h = z & 15;
  int p0 = blockIdx.x * 32, s0 = blockIdx.y * 32;
  int tx = threadIdx.x & 31, ty = threadIdx.x >> 5;
#pragma unroll
  for (int i = 0; i < 4; ++i) {
    int s = s0 + ty + i * 8;
    tile[ty + i * 8][tx] = qkvb[(size_t)(b * 512 + s) * 3072 + 2048 + h * 64 + p0 + tx];
  }
  __syncthreads();
#pragma unroll
  for (int i = 0; i < 4; ++i) {
    int p = ty + i * 8;
    vt[((size_t)z * 64 + p0 + p) * 512 + s0 + tx] = tile[tx][p];
  }
}

// ---------------- fused flash attention ----------------
__global__ __launch_bounds__(256) void k_attn(const u16* __restrict__ qkvb, const u16* __restrict__ vt,
                                              u16* __restrict__ ctxb) {
  __shared__ __align__(16) u16 Qs[64 * 64];
  __shared__ __align__(16) u16 Ks[64 * 64];
  __shared__ __align__(16) u16 Vts[64 * 64];
  __shared__ __align__(16) u16 Ps[4 * 16 * 64];
  const int tid = threadIdx.x, lane = tid & 63, wid = tid >> 6;
  const int g = lane >> 4, r16 = lane & 15;
  const int z = blockIdx.y, b = z >> 4, h = z & 15;
  const int qt = blockIdx.x;
  const float CF = 0.125f * 1.44269504089f;

#pragma unroll
  for (int it = 0; it < 2; ++it) {
    int q = it * 4096 + tid * 16;
    int row = q >> 7, colb = q & 127;
    int scol = colb ^ ((row & 7) << 4);
    gll16((const char*)qkvb + ((size_t)(b * 512 + qt * 64 + row) * 3072 + h * 64) * 2 + scol,
          (const char*)Qs + it * 4096 + wid * 1024);
  }
  __syncthreads();
  bf16x8 aq[2];
  {
    int rowl = wid * 16 + r16;
#pragma unroll
    for (int kk = 0; kk < 2; ++kk)
      aq[kk] = *(const bf16x8*)(Qs + rowl * 64 + ((kk * 32 + g * 8) ^ ((rowl & 7) << 3)));
  }

  f32x4 o[4];
#pragma unroll
  for (int pi = 0; pi < 4; ++pi) o[pi] = {0.f, 0.f, 0.f, 0.f};
  float m4[4], l4[4];
#pragma unroll
  for (int j = 0; j < 4; ++j) { m4[j] = -1e30f; l4[j] = 0.f; }

  for (int kt = 0; kt < 8; ++kt) {
#pragma unroll
    for (int it = 0; it < 2; ++it) {
      int q = it * 4096 + tid * 16;
      int row = q >> 7, colb = q & 127;
      int scol = colb ^ ((row & 7) << 4);
      gll16((const char*)qkvb + ((size_t)(b * 512 + kt * 64 + row) * 3072 + 1024 + h * 64) * 2 + scol,
            (const char*)Ks + it * 4096 + wid * 1024);
      gll16((const char*)vt + ((size_t)(z * 64 + row) * 512 + kt * 64) * 2 + scol,
            (const char*)Vts + it * 4096 + wid * 1024);
    }
    __syncthreads();

    f32x4 s[4];
#pragma unroll
    for (int nj = 0; nj < 4; ++nj) s[nj] = {0.f, 0.f, 0.f, 0.f};
#pragma unroll
    for (int kk = 0; kk < 2; ++kk) {
#pragma unroll
      for (int nj = 0; nj < 4; ++nj) {
        int rowk = nj * 16 + r16;
        bf16x8 bk = *(const bf16x8*)(Ks + rowk * 64 + ((kk * 32 + g * 8) ^ ((rowk & 7) << 3)));
        s[nj] = __builtin_amdgcn_mfma_f32_16x16x32_bf16(aq[kk], bk, s[nj], 0, 0, 0);
      }
    }

    float scale[4];
#pragma unroll
    for (int j = 0; j < 4; ++j) {
      float pm = fmaxf(fmaxf(s[0][j], s[1][j]), fmaxf(s[2][j], s[3][j]));
      pm = fmaxf(pm, __shfl_xor(pm, 1));
      pm = fmaxf(pm, __shfl_xor(pm, 2));
      pm = fmaxf(pm, __shfl_xor(pm, 4));
      pm = fmaxf(pm, __shfl_xor(pm, 8));
      float mn = fmaxf(m4[j], pm);
      scale[j] = exp2f((m4[j] - mn) * CF);
      m4[j] = mn;
      int rowp = g * 4 + j;
      u16* pbase = Ps + wid * 1024 + rowp * 64;
      int sw = (rowp & 7) << 3;
      float ps = 0.f;
#pragma unroll
      for (int nj = 0; nj < 4; ++nj) {
        float p = exp2f((s[nj][j] - mn) * CF);
        ps += p;
        pbase[(nj * 16 + r16) ^ sw] = f2bf(p);
      }
      ps += __shfl_xor(ps, 1); ps += __shfl_xor(ps, 2);
      ps += __shfl_xor(ps, 4); ps += __shfl_xor(ps, 8);
      l4[j] = l4[j] * scale[j] + ps;
    }
#pragma unroll
    for (int pi = 0; pi < 4; ++pi)
#pragma unroll
      for (int j = 0; j < 4; ++j) o[pi][j] *= scale[j];

    asm volatile("s_waitcnt lgkmcnt(0)" ::: "memory");

#pragma unroll
    for (int kk = 0; kk < 2; ++kk) {
      bf16x8 ap = *(const bf16x8*)(Ps + wid * 1024 + r16 * 64 + ((kk * 32 + g * 8) ^ ((r16 & 7) << 3)));
#pragma unroll
      for (int pi = 0; pi < 4; ++pi) {
        int rowv = pi * 16 + r16;
        bf16x8 bv = *(const bf16x8*)(Vts + rowv * 64 + ((kk * 32 + g * 8) ^ ((rowv & 7) << 3)));
        o[pi] = __builtin_amdgcn_mfma_f32_16x16x32_bf16(ap, bv, o[pi], 0, 0, 0);
      }
    }
    __syncthreads();
  }

#pragma unroll
  for (int j = 0; j < 4; ++j) {
    float inv = 1.f / l4[j];
    int token = b * 512 + qt * 64 + wid * 16 + g * 4 + j;
#pragma unroll
    for (int pi = 0; pi < 4; ++pi)
      ctxb[(size_t)token * 1024 + h * 64 + pi * 16 + r16] = f2bf(o[pi][j] * inv);
  }
}

// ---------------- fused (2-partial sum) + bias + residual + LayerNorm ----------------
__global__ __launch_bounds__(256) void k_ln3(const float* __restrict__ a0, const float* __restrict__ a1,
                                             const float* __restrict__ res, const float* __restrict__ bvec,
                                             const float* __restrict__ gamma, const float* __restrict__ beta,
                                             float* __restrict__ outf, u16* __restrict__ outb) {
  __shared__ float sb[8];
  int row = blockIdx.x, t = threadIdx.x, lane = t & 63, wid = t >> 6;
  const size_t rb = (size_t)row * 1024 + t * 4;
  float4 p0 = *(const float4*)(a0 + rb);
  float4 p1 = *(const float4*)(a1 + rb);
  float4 rv = *(const float4*)(res + rb);
  float4 bb = *(const float4*)(bvec + t * 4);
  float v[4] = {p0.x + p1.x + rv.x + bb.x, p0.y + p1.y + rv.y + bb.y,
                p0.z + p1.z + rv.z + bb.z, p0.w + p1.w + rv.w + bb.w};
  float s = v[0] + v[1] + v[2] + v[3];
  s = wredsum(s);
  if (lane == 0) sb[wid] = s;
  __syncthreads();
  float mu = (sb[0] + sb[1] + sb[2] + sb[3]) * (1.f / 1024.f);
  float q = 0.f;
#pragma unroll
  for (int i = 0; i < 4; ++i) { float d = v[i] - mu; q += d * d; }
  q = wredsum(q);
  if (lane == 0) sb[4 + wid] = q;
  __syncthreads();
  float rstd = rsqrtf((sb[4] + sb[5] + sb[6] + sb[7]) * (1.f / 1024.f) + 1e-5f);
  float4 gv = *(const float4*)(gamma + t * 4);
  float4 bt = *(const float4*)(beta + t * 4);
  float ov[4];
  ov[0] = (v[0] - mu) * rstd * gv.x + bt.x;
  ov[1] = (v[1] - mu) * rstd * gv.y + bt.y;
  ov[2] = (v[2] - mu) * rstd * gv.z + bt.z;
  ov[3] = (v[3] - mu) * rstd * gv.w + bt.w;
  *(float4*)(outf + rb) = {ov[0], ov[1], ov[2], ov[3]};
  if (outb) {
    ushort4 ob = {f2bf(ov[0]), f2bf(ov[1]), f2bf(ov[2]), f2bf(ov[3])};
    *(ushort4*)(outb + rb) = ob;
  }
}

// ---------------- orchestration (R3 layout — best known good) ----------------
// Workspace map (MB), time-multiplexed:
//   [0,6) wqkvb -> ffn2 p1 [0,16) | [6,8) woutb | [8,16) wffn1b | [16,24) wffn2b
//   [24,32) xb/ctxb/r1b | [32,56) qkvb -> q1 [32,48) -> hb [32,64)
//   [56,64) vt | [64,80) q0 -> p0 (fp32) | r1 fp32 in d_out. Peak 80 MB.
extern "C" void kernel_launch(void* const* d_in, const int* in_sizes, int n_in,
                              void* d_out, int out_size, void* d_ws, size_t ws_size,
                              hipStream_t stream) {
  const float* x      = (const float*)d_in[0];
  const float* w_qkv  = (const float*)d_in[1];
  const float* b_qkv  = (const float*)d_in[2];
  const float* w_out  = (const float*)d_in[3];
  const float* b_out  = (const float*)d_in[4];
  const float* ln1s   = (const float*)d_in[5];
  const float* ln1b   = (const float*)d_in[6];
  const float* w_ffn1 = (const float*)d_in[7];
  const float* b_ffn1 = (const float*)d_in[8];
  const float* w_ffn2 = (const float*)d_in[9];
  const float* b_ffn2 = (const float*)d_in[10];
  const float* ln2s   = (const float*)d_in[11];
  const float* ln2b   = (const float*)d_in[12];

  char* ws = (char*)d_ws;
  const size_t MB = 1024 * 1024;
  u16* wqkvb   = (u16*)(ws + 0 * MB);
  u16* woutb   = (u16*)(ws + 6 * MB);
  u16* wffn1b  = (u16*)(ws + 8 * MB);
  u16* wffn2b  = (u16*)(ws + 16 * MB);
  u16* xb      = (u16*)(ws + 24 * MB);
  u16* ctxb    = xb;
  u16* r1b     = xb;
  u16* qkvb    = (u16*)(ws + 32 * MB);
  u16* hb      = (u16*)(ws + 32 * MB);
  u16* vt      = (u16*)(ws + 56 * MB);
  float* q0    = (float*)(ws + 64 * MB);
  float* q1    = (float*)(ws + 32 * MB);
  float* p0    = (float*)(ws + 64 * MB);
  float* p1    = (float*)(ws + 0 * MB);
  float* r1    = (float*)d_out;
  float* outp  = (float*)d_out;

  // pack weights (transpose to [N][K] bf16)
  k_tcvt<<<dim3(32, 32, 3), 256, 0, stream>>>(w_qkv, wqkvb, 1024, 1024, 1024 * 1024, 1024 * 1024);
  k_tcvt<<<dim3(32, 32, 1), 256, 0, stream>>>(w_out, woutb, 1024, 1024, 0, 0);
  k_tcvt<<<dim3(128, 32, 1), 256, 0, stream>>>(w_ffn1, wffn1b, 1024, 4096, 0, 0);
  k_tcvt<<<dim3(32, 128, 1), 256, 0, stream>>>(w_ffn2, wffn2b, 4096, 1024, 0, 0);
  k_cvt<<<4096, 256, 0, stream>>>(x, xb, 1048576);

  // qkv = x @ w_qkv + b_qkv  (bf16 out): grid 24x16 = 384 blocks, nk=32
  k_gemmD<1><<<dim3(24 * 16), 512, 0, stream>>>(xb, wqkvb, b_qkv, qkvb, 0, 4096, 3072, 1024, 1024);
  k_build_vt<<<dim3(2, 16, 128), 256, 0, stream>>>(qkvb, vt);
  k_attn<<<dim3(8, 128), 256, 0, stream>>>(qkvb, vt, ctxb);

  // attn_out = ctx @ w_out (split-K=2: 8x16x2 = 256 blocks, nk=16, fp32 partials)
  k_gemmD<0><<<dim3(8 * 16 * 2), 512, 0, stream>>>(ctxb, woutb, nullptr, q0, (long)(q1 - q0),
                                                   4096, 1024, 1024, 512);
  // r1 = LN(x + q0 + q1 + b_out) -> fp32 (d_out) + bf16
  k_ln3<<<4096, 256, 0, stream>>>(q0, q1, x, b_out, ln1s, ln1b, r1, r1b);

  // h = gelu(r1 @ w_ffn1 + b_ffn1): grid 32x16 = 512 blocks, nk=32
  k_gemmD<2><<<dim3(32 * 16), 512, 0, stream>>>(r1b, wffn1b, b_ffn1, hb, 0, 4096, 4096, 1024, 1024);

  // ffn_out = h @ w_ffn2 (split-K=2: 256 blocks, nk=64, fp32 partials)
  k_gemmD<0><<<dim3(8 * 16 * 2), 512, 0, stream>>>(hb, wffn2b, nullptr, p0, (long)(p1 - p0),
                                                   4096, 1024, 4096, 2048);
  // out = LN(r1 + p0 + p1 + b_ffn2)
  k_ln3<<<4096, 256, 0, stream>>>(p0, p1, r1, b_ffn2, ln2s, ln2b, outp, (u16*)nullptr);
}

// Round 10
// 250.893 us; speedup vs baseline: 1.3454x; 1.2912x over previous
//
#include <hip/hip_runtime.h>
#include <cstdint>
#include <cstddef>

typedef unsigned short u16;
typedef unsigned int u32;
typedef __bf16 bf16x8 __attribute__((ext_vector_type(8)));
typedef float f32x4 __attribute__((ext_vector_type(4)));

#define DEVI static __device__ __forceinline__

// round-to-nearest-even fp32 -> bf16
DEVI u16 f2bf(float f) {
  u32 u = __builtin_bit_cast(u32, f);
  u = (u + 0x7fffu + ((u >> 16) & 1u)) >> 16;
  return (u16)u;
}
DEVI float bf2f(u16 u) { return __builtin_bit_cast(float, (u32)u << 16); }

// async global->LDS, 16B per lane. LDS dest is wave-uniform base + lane*16.
DEVI void gll16(const void* gsrc, const void* ldst) {
  __builtin_amdgcn_global_load_lds(
      (const __attribute__((address_space(1))) u32*)(uintptr_t)gsrc,
      (__attribute__((address_space(3))) u32*)(u32)(uintptr_t)ldst, 16, 0, 0);
}

DEVI float wredsum(float v) {
  v += __shfl_xor(v, 32); v += __shfl_xor(v, 16); v += __shfl_xor(v, 8);
  v += __shfl_xor(v, 4);  v += __shfl_xor(v, 2);  v += __shfl_xor(v, 1);
  return v;
}

// raw s_barrier with compiler memory fences (no vmcnt drain!)
DEVI void barx() {
  asm volatile("" ::: "memory");
  __builtin_amdgcn_s_barrier();
  asm volatile("" ::: "memory");
}

// ---------------- transpose + cvt: fp32 [R][C] -> bf16 [C][R] ----------------
__global__ __launch_bounds__(256) void k_tcvt(const float* __restrict__ in, u16* __restrict__ out,
                                              int R, int C, long in_z, long out_z) {
  __shared__ float tile[32][33];
  const float* inp = in + (long)blockIdx.z * in_z;
  u16* outp = out + (long)blockIdx.z * out_z;
  int c0 = blockIdx.x * 32, r0 = blockIdx.y * 32;
  int tx = threadIdx.x & 31, ty = threadIdx.x >> 5;
#pragma unroll
  for (int i = 0; i < 4; ++i)
    tile[ty + i * 8][tx] = inp[(long)(r0 + ty + i * 8) * C + c0 + tx];
  __syncthreads();
#pragma unroll
  for (int i = 0; i < 4; ++i) {
    int cc = ty + i * 8;
    outp[(long)(c0 + cc) * R + r0 + tx] = f2bf(tile[tx][cc]);
  }
}

// ---------------- elementwise fp32 -> bf16 ----------------
__global__ __launch_bounds__(256) void k_cvt(const float* __restrict__ in, u16* __restrict__ out, int n4) {
  int i = blockIdx.x * 256 + threadIdx.x;
  if (i >= n4) return;
  float4 v = ((const float4*)in)[i];
  ushort4 o;
  o.x = f2bf(v.x); o.y = f2bf(v.y); o.z = f2bf(v.z); o.w = f2bf(v.w);
  ((ushort4*)out)[i] = o;
}

// ============ R3's proven deep-pipelined bf16 GEMM (best measured: 530 TF) ============
// C = A[M][K] * Bt[N][K]^T (+bias). Tile 256x128, BK=64, 8 waves (4M x 2N),
// per-wave 64x64 output. LDS 96KB: 2 buf x (A 32KB + B 16KB), XOR-swizzled
// row-major 128B rows (coalesced staging: 8 lanes cover one row's 128B).
// Stage units (16KB, 2 loads/thread): P1 stages B(x+1); P2 stages Ah0/Ah1(x+2);
// counted s_waitcnt vmcnt(4) once per K-tile (drain at x=nk-2). nk >= 2.
// Split-K via blockIdx z-slice: output at Cout + z*pofs (elements).
// EPI: 0 = fp32 out, 1 = bf16 out (+bias), 2 = exact-GELU -> bf16 (+bias)
template <int EPI>
__global__ __launch_bounds__(512, 2) void k_gemm8(const u16* __restrict__ A, const u16* __restrict__ Bt,
                                                  const float* __restrict__ bias, void* __restrict__ Cout,
                                                  long pofs, int M, int N, int K, int Kc) {
  __shared__ __align__(16) u16 lds[49152];  // 96 KB
  char* Lc = (char*)&lds[0];
  const int tid = threadIdx.x;
  const int lane = tid & 63, wid = tid >> 6;
  const int wr = wid >> 1, wc = wid & 1;   // 4 M-waves x 2 N-waves
  const int g = lane >> 4, r16 = lane & 15;

  // bijective XCD swizzle (grid % 8 == 0 for all launches)
  const int gx = N >> 7, gy = M >> 8;
  const int cpx = (int)gridDim.x >> 3;
  int bb = blockIdx.x;
  int id = (bb & 7) * cpx + (bb >> 3);
  const int gxy = gx * gy;
  const int bz = id / gxy;
  int rr = id - bz * gxy;
  const int by = rr / gx;
  const int bx = rr - by * gx;
  const long row0 = (long)by * 256;
  const long col0 = (long)bx * 128;
  const long kbeg = (long)bz * Kc;
  const int nk = Kc >> 6;  // BK=64 K-tiles

  const size_t KB = (size_t)K * 2;  // row stride in bytes
  const char* Ab = (const char*)A + (size_t)row0 * KB + (size_t)kbeg * 2;
  const char* Bb = (const char*)Bt + (size_t)col0 * KB + (size_t)kbeg * 2;

  // stage one 16KB unit (128 rows x 128B): 2 gll16/thread, linear LDS dest,
  // inverse-swizzled global source: src = dest ^ ((destrow&7)<<4)
#define STAGE(gb, ldsoff)                                                        \
  do {                                                                           \
    _Pragma("unroll") for (int i_ = 0; i_ < 2; ++i_) {                           \
      int dq_ = i_ * 8192 + tid * 16;                                            \
      int sq_ = dq_ ^ (((dq_ >> 7) & 7) << 4);                                   \
      gll16((gb) + (size_t)(sq_ >> 7) * KB + (sq_ & 127),                        \
            Lc + (ldsoff) + i_ * 8192 + wid * 1024);                             \
    }                                                                            \
  } while (0)

  f32x4 acc[4][4];
#pragma unroll
  for (int i = 0; i < 4; ++i)
#pragma unroll
    for (int j = 0; j < 4; ++j) acc[i][j] = {0.f, 0.f, 0.f, 0.f};

  // prologue: tile0 {Ah0,Ah1,B} -> buf0; tile1 {Ah0,Ah1} -> buf1 (10 loads)
  STAGE(Ab, 0);
  STAGE(Ab + 128 * KB, 16384);
  STAGE(Bb, 32768);
  STAGE(Ab + 128, 49152);
  STAGE(Ab + 128 * KB + 128, 49152 + 16384);
  asm volatile("s_waitcnt vmcnt(4)" ::: "memory");  // tile0 resident; tile1 A in flight
  barx();

  // per-thread constant addressing: row&7 == r16&7 (all other terms are %8==0)
  const int swz = (r16 & 7) << 4;
  const int arow = (wr >> 1) * 16384 + ((wr & 1) * 64 + r16) * 128;  // + m*2048
  const int brow = 32768 + (wc * 64 + r16) * 128;                    // + n*2048

  for (int x = 0; x < nk; ++x) {
    const int buf = (x & 1) ? 49152 : 0;
    const int obuf = 49152 - buf;
    // -------- P1: read all A-frags + B n0..1; stage B(x+1); MFMA n0..1 --------
    bf16x8 aF[4][2], bF0[2][2];
#pragma unroll
    for (int m = 0; m < 4; ++m)
#pragma unroll
      for (int ks = 0; ks < 2; ++ks)
        aF[m][ks] = *(const bf16x8*)(Lc + buf + arow + m * 2048 + ((ks * 64 + g * 16) ^ swz));
#pragma unroll
    for (int n = 0; n < 2; ++n)
#pragma unroll
      for (int ks = 0; ks < 2; ++ks)
        bF0[n][ks] = *(const bf16x8*)(Lc + buf + brow + n * 2048 + ((ks * 64 + g * 16) ^ swz));
    if (x + 1 < nk) STAGE(Bb + (size_t)(x + 1) * 128, obuf + 32768);
    barx();
    __builtin_amdgcn_s_setprio(1);
#pragma unroll
    for (int ks = 0; ks < 2; ++ks)
#pragma unroll
      for (int m = 0; m < 4; ++m)
#pragma unroll
        for (int n = 0; n < 2; ++n)
          acc[m][n] = __builtin_amdgcn_mfma_f32_16x16x32_bf16(aF[m][ks], bF0[n][ks], acc[m][n], 0, 0, 0);
    __builtin_amdgcn_s_setprio(0);
    barx();  // protects other waves' in-flight P1 ds_reads from P2's A-stage clobber
    // -------- P2: read B n2..3; stage Ah0/Ah1(x+2); counted vmcnt; MFMA n2..3 --------
    bf16x8 bF1[2][2];
#pragma unroll
    for (int n = 0; n < 2; ++n)
#pragma unroll
      for (int ks = 0; ks < 2; ++ks)
        bF1[n][ks] = *(const bf16x8*)(Lc + buf + brow + (n + 2) * 2048 + ((ks * 64 + g * 16) ^ swz));
    if (x + 2 < nk) {
      STAGE(Ab + (size_t)(x + 2) * 128, buf);
      STAGE(Ab + 128 * KB + (size_t)(x + 2) * 128, buf + 16384);
    }
    if (x < nk - 2) {
      asm volatile("s_waitcnt vmcnt(4)" ::: "memory");  // tile x+1 fully resident
    } else if (x == nk - 2) {
      asm volatile("s_waitcnt vmcnt(0)" ::: "memory");  // final drain
    }
    barx();
    __builtin_amdgcn_s_setprio(1);
#pragma unroll
    for (int ks = 0; ks < 2; ++ks)
#pragma unroll
      for (int m = 0; m < 4; ++m)
#pragma unroll
        for (int n = 0; n < 2; ++n)
          acc[m][n + 2] = __builtin_amdgcn_mfma_f32_16x16x32_bf16(aF[m][ks], bF1[n][ks], acc[m][n + 2], 0, 0, 0);
    __builtin_amdgcn_s_setprio(0);
    barx();
  }
#undef STAGE

  // epilogue: C/D mapping col=lane&15, row=(lane>>4)*4+j
  float* outf = (float*)Cout + (long)bz * pofs;
  u16* outh = (u16*)Cout + (long)bz * pofs;
#pragma unroll
  for (int n = 0; n < 4; ++n) {
    long col = col0 + wc * 64 + n * 16 + r16;
    float bv = bias ? bias[col] : 0.f;
#pragma unroll
    for (int m = 0; m < 4; ++m) {
      long rowb = row0 + wr * 64 + m * 16 + g * 4;
#pragma unroll
      for (int j = 0; j < 4; ++j) {
        float v = acc[m][n][j] + bv;
        size_t off = (size_t)(rowb + j) * N + col;
        if (EPI == 0) {
          outf[off] = v;
        } else if (EPI == 1) {
          outh[off] = f2bf(v);
        } else {
          float gl = 0.5f * v * (1.f + erff(v * 0.70710678118f));
          outh[off] = f2bf(gl);
        }
      }
    }
  }
}

// ---------------- build V^T: qkvb[token][2048+h*64+p] -> vt[(b,h)][p][s] ----------------
__global__ __launch_bounds__(256) void k_build_vt(const u16* __restrict__ qkvb, u16* __restrict__ vt) {
  __shared__ u16 tile[32][33];
  int z = blockIdx.z, b = z >> 4, h = z & 15;
  int p0 = blockIdx.x * 32, s0 = blockIdx.y * 32;
  int tx = threadIdx.x & 31, ty = threadIdx.x >> 5;
#pragma unroll
  for (int i = 0; i < 4; ++i) {
    int s = s0 + ty + i * 8;
    tile[ty + i * 8][tx] = qkvb[(size_t)(b * 512 + s) * 3072 + 2048 + h * 64 + p0 + tx];
  }
  __syncthreads();
#pragma unroll
  for (int i = 0; i < 4; ++i) {
    int p = ty + i * 8;
    vt[((size_t)z * 64 + p0 + p) * 512 + s0 + tx] = tile[tx][p];
  }
}

// ---------------- fused flash attention ----------------
__global__ __launch_bounds__(256) void k_attn(const u16* __restrict__ qkvb, const u16* __restrict__ vt,
                                              u16* __restrict__ ctxb) {
  __shared__ __align__(16) u16 Qs[64 * 64];
  __shared__ __align__(16) u16 Ks[64 * 64];
  __shared__ __align__(16) u16 Vts[64 * 64];
  __shared__ __align__(16) u16 Ps[4 * 16 * 64];
  const int tid = threadIdx.x, lane = tid & 63, wid = tid >> 6;
  const int g = lane >> 4, r16 = lane & 15;
  const int z = blockIdx.y, b = z >> 4, h = z & 15;
  const int qt = blockIdx.x;
  const float CF = 0.125f * 1.44269504089f;

#pragma unroll
  for (int it = 0; it < 2; ++it) {
    int q = it * 4096 + tid * 16;
    int row = q >> 7, colb = q & 127;
    int scol = colb ^ ((row & 7) << 4);
    gll16((const char*)qkvb + ((size_t)(b * 512 + qt * 64 + row) * 3072 + h * 64) * 2 + scol,
          (const char*)Qs + it * 4096 + wid * 1024);
  }
  __syncthreads();
  bf16x8 aq[2];
  {
    int rowl = wid * 16 + r16;
#pragma unroll
    for (int kk = 0; kk < 2; ++kk)
      aq[kk] = *(const bf16x8*)(Qs + rowl * 64 + ((kk * 32 + g * 8) ^ ((rowl & 7) << 3)));
  }

  f32x4 o[4];
#pragma unroll
  for (int pi = 0; pi < 4; ++pi) o[pi] = {0.f, 0.f, 0.f, 0.f};
  float m4[4], l4[4];
#pragma unroll
  for (int j = 0; j < 4; ++j) { m4[j] = -1e30f; l4[j] = 0.f; }

  for (int kt = 0; kt < 8; ++kt) {
#pragma unroll
    for (int it = 0; it < 2; ++it) {
      int q = it * 4096 + tid * 16;
      int row = q >> 7, colb = q & 127;
      int scol = colb ^ ((row & 7) << 4);
      gll16((const char*)qkvb + ((size_t)(b * 512 + kt * 64 + row) * 3072 + 1024 + h * 64) * 2 + scol,
            (const char*)Ks + it * 4096 + wid * 1024);
      gll16((const char*)vt + ((size_t)(z * 64 + row) * 512 + kt * 64) * 2 + scol,
            (const char*)Vts + it * 4096 + wid * 1024);
    }
    __syncthreads();

    f32x4 s[4];
#pragma unroll
    for (int nj = 0; nj < 4; ++nj) s[nj] = {0.f, 0.f, 0.f, 0.f};
#pragma unroll
    for (int kk = 0; kk < 2; ++kk) {
#pragma unroll
      for (int nj = 0; nj < 4; ++nj) {
        int rowk = nj * 16 + r16;
        bf16x8 bk = *(const bf16x8*)(Ks + rowk * 64 + ((kk * 32 + g * 8) ^ ((rowk & 7) << 3)));
        s[nj] = __builtin_amdgcn_mfma_f32_16x16x32_bf16(aq[kk], bk, s[nj], 0, 0, 0);
      }
    }

    float scale[4];
#pragma unroll
    for (int j = 0; j < 4; ++j) {
      float pm = fmaxf(fmaxf(s[0][j], s[1][j]), fmaxf(s[2][j], s[3][j]));
      pm = fmaxf(pm, __shfl_xor(pm, 1));
      pm = fmaxf(pm, __shfl_xor(pm, 2));
      pm = fmaxf(pm, __shfl_xor(pm, 4));
      pm = fmaxf(pm, __shfl_xor(pm, 8));
      float mn = fmaxf(m4[j], pm);
      scale[j] = exp2f((m4[j] - mn) * CF);
      m4[j] = mn;
      int rowp = g * 4 + j;
      u16* pbase = Ps + wid * 1024 + rowp * 64;
      int sw = (rowp & 7) << 3;
      float ps = 0.f;
#pragma unroll
      for (int nj = 0; nj < 4; ++nj) {
        float p = exp2f((s[nj][j] - mn) * CF);
        ps += p;
        pbase[(nj * 16 + r16) ^ sw] = f2bf(p);
      }
      ps += __shfl_xor(ps, 1); ps += __shfl_xor(ps, 2);
      ps += __shfl_xor(ps, 4); ps += __shfl_xor(ps, 8);
      l4[j] = l4[j] * scale[j] + ps;
    }
#pragma unroll
    for (int pi = 0; pi < 4; ++pi)
#pragma unroll
      for (int j = 0; j < 4; ++j) o[pi][j] *= scale[j];

    asm volatile("s_waitcnt lgkmcnt(0)" ::: "memory");

#pragma unroll
    for (int kk = 0; kk < 2; ++kk) {
      bf16x8 ap = *(const bf16x8*)(Ps + wid * 1024 + r16 * 64 + ((kk * 32 + g * 8) ^ ((r16 & 7) << 3)));
#pragma unroll
      for (int pi = 0; pi < 4; ++pi) {
        int rowv = pi * 16 + r16;
        bf16x8 bv = *(const bf16x8*)(Vts + rowv * 64 + ((kk * 32 + g * 8) ^ ((rowv & 7) << 3)));
        o[pi] = __builtin_amdgcn_mfma_f32_16x16x32_bf16(ap, bv, o[pi], 0, 0, 0);
      }
    }
    __syncthreads();
  }

#pragma unroll
  for (int j = 0; j < 4; ++j) {
    float inv = 1.f / l4[j];
    int token = b * 512 + qt * 64 + wid * 16 + g * 4 + j;
#pragma unroll
    for (int pi = 0; pi < 4; ++pi)
      ctxb[(size_t)token * 1024 + h * 64 + pi * 16 + r16] = f2bf(o[pi][j] * inv);
  }
}

// ---------------- fused (4 bf16 partials) + bias + residual + LayerNorm ----------------
__global__ __launch_bounds__(256) void k_ln4(const u16* __restrict__ p, long pofs,
                                             const float* __restrict__ res, const float* __restrict__ bvec,
                                             const float* __restrict__ gamma, const float* __restrict__ beta,
                                             float* __restrict__ outf, u16* __restrict__ outb) {
  __shared__ float sb[8];
  int row = blockIdx.x, t = threadIdx.x, lane = t & 63, wid = t >> 6;
  const size_t rb = (size_t)row * 1024 + t * 4;
  float4 rv = *(const float4*)(res + rb);
  float4 bb = *(const float4*)(bvec + t * 4);
  float v[4] = {rv.x + bb.x, rv.y + bb.y, rv.z + bb.z, rv.w + bb.w};
#pragma unroll
  for (int z = 0; z < 4; ++z) {
    ushort4 u = *(const ushort4*)(p + (size_t)z * pofs + rb);
    v[0] += bf2f(u.x); v[1] += bf2f(u.y); v[2] += bf2f(u.z); v[3] += bf2f(u.w);
  }
  float s = v[0] + v[1] + v[2] + v[3];
  s = wredsum(s);
  if (lane == 0) sb[wid] = s;
  __syncthreads();
  float mu = (sb[0] + sb[1] + sb[2] + sb[3]) * (1.f / 1024.f);
  float q = 0.f;
#pragma unroll
  for (int i = 0; i < 4; ++i) { float d = v[i] - mu; q += d * d; }
  q = wredsum(q);
  if (lane == 0) sb[4 + wid] = q;
  __syncthreads();
  float rstd = rsqrtf((sb[4] + sb[5] + sb[6] + sb[7]) * (1.f / 1024.f) + 1e-5f);
  float4 gv = *(const float4*)(gamma + t * 4);
  float4 bt = *(const float4*)(beta + t * 4);
  float ov[4];
  ov[0] = (v[0] - mu) * rstd * gv.x + bt.x;
  ov[1] = (v[1] - mu) * rstd * gv.y + bt.y;
  ov[2] = (v[2] - mu) * rstd * gv.z + bt.z;
  ov[3] = (v[3] - mu) * rstd * gv.w + bt.w;
  *(float4*)(outf + rb) = {ov[0], ov[1], ov[2], ov[3]};
  if (outb) {
    ushort4 ob = {f2bf(ov[0]), f2bf(ov[1]), f2bf(ov[2]), f2bf(ov[3])};
    *(ushort4*)(outb + rb) = ob;
  }
}

// ---------------- orchestration ----------------
// Workspace map (MB), time-multiplexed (R4 layout, validated R6-R8):
//   [0,6) wqkvb | [6,8) woutb | [8,16) wffn1b | [16,24) free | [24,32) xb/ctxb/r1b
//   [32,56) qkvb -> qp0..2 -> hb | [56,64) vt -> qp3 -> hb | [64,72) free
//   [72,80) wffn2b.  qp0..3 @ [32,64) stride 8MB; pp0..3 @ [0,32) stride 8MB.
//   r1 fp32 in d_out. Peak 80 MB.
extern "C" void kernel_launch(void* const* d_in, const int* in_sizes, int n_in,
                              void* d_out, int out_size, void* d_ws, size_t ws_size,
                              hipStream_t stream) {
  const float* x      = (const float*)d_in[0];
  const float* w_qkv  = (const float*)d_in[1];
  const float* b_qkv  = (const float*)d_in[2];
  const float* w_out  = (const float*)d_in[3];
  const float* b_out  = (const float*)d_in[4];
  const float* ln1s   = (const float*)d_in[5];
  const float* ln1b   = (const float*)d_in[6];
  const float* w_ffn1 = (const float*)d_in[7];
  const float* b_ffn1 = (const float*)d_in[8];
  const float* w_ffn2 = (const float*)d_in[9];
  const float* b_ffn2 = (const float*)d_in[10];
  const float* ln2s   = (const float*)d_in[11];
  const float* ln2b   = (const float*)d_in[12];

  char* ws = (char*)d_ws;
  const size_t MB = 1024 * 1024;
  u16* wqkvb   = (u16*)(ws + 0 * MB);
  u16* woutb   = (u16*)(ws + 6 * MB);
  u16* wffn1b  = (u16*)(ws + 8 * MB);
  u16* wffn2b  = (u16*)(ws + 72 * MB);
  u16* xb      = (u16*)(ws + 24 * MB);
  u16* ctxb    = xb;
  u16* r1b     = xb;
  u16* qkvb    = (u16*)(ws + 32 * MB);
  u16* vt      = (u16*)(ws + 56 * MB);
  u16* qp      = (u16*)(ws + 32 * MB);   // 4 bf16 partials, stride 8MB
  u16* hb      = (u16*)(ws + 32 * MB);
  u16* pp      = (u16*)(ws + 0 * MB);    // 4 bf16 partials, stride 8MB
  float* r1    = (float*)d_out;
  float* outp  = (float*)d_out;
  const long PSTRIDE = 4096L * 1024L;    // elements per bf16 partial (8MB)

  // pack weights (transpose to [N][K] bf16)
  k_tcvt<<<dim3(32, 32, 3), 256, 0, stream>>>(w_qkv, wqkvb, 1024, 1024, 1024 * 1024, 1024 * 1024);
  k_tcvt<<<dim3(32, 32, 1), 256, 0, stream>>>(w_out, woutb, 1024, 1024, 0, 0);
  k_tcvt<<<dim3(128, 32, 1), 256, 0, stream>>>(w_ffn1, wffn1b, 1024, 4096, 0, 0);
  k_tcvt<<<dim3(32, 128, 1), 256, 0, stream>>>(w_ffn2, wffn2b, 4096, 1024, 0, 0);
  k_cvt<<<4096, 256, 0, stream>>>(x, xb, 1048576);

  // qkv = x @ w_qkv + b_qkv  (bf16 out): grid 24x16 = 384 blocks, nk=16
  k_gemm8<1><<<dim3(24 * 16), 512, 0, stream>>>(xb, wqkvb, b_qkv, qkvb, 0, 4096, 3072, 1024, 1024);
  k_build_vt<<<dim3(2, 16, 128), 256, 0, stream>>>(qkvb, vt);
  k_attn<<<dim3(8, 128), 256, 0, stream>>>(qkvb, vt, ctxb);

  // attn_out partials = ctx @ w_out (split-K=4: 8x16x4 = 512 blocks, nk=4, bf16 partials)
  k_gemm8<1><<<dim3(8 * 16 * 4), 512, 0, stream>>>(ctxb, woutb, nullptr, qp, PSTRIDE,
                                                   4096, 1024, 1024, 256);
  // r1 = LN(x + sum(qp) + b_out) -> fp32 (d_out) + bf16
  k_ln4<<<4096, 256, 0, stream>>>(qp, PSTRIDE, x, b_out, ln1s, ln1b, r1, r1b);

  // h = gelu(r1 @ w_ffn1 + b_ffn1): grid 32x16 = 512 blocks, nk=16
  k_gemm8<2><<<dim3(32 * 16), 512, 0, stream>>>(r1b, wffn1b, b_ffn1, hb, 0, 4096, 4096, 1024, 1024);

  // ffn2 partials = h @ w_ffn2 (split-K=4: 512 blocks, nk=16, bf16 partials)
  k_gemm8<1><<<dim3(8 * 16 * 4), 512, 0, stream>>>(hb, wffn2b, nullptr, pp, PSTRIDE,
                                                   4096, 1024, 4096, 1024);
  // out = LN(r1 + sum(pp) + b_ffn2)
  k_ln4<<<4096, 256, 0, stream>>>(pp, PSTRIDE, r1, b_ffn2, ln2s, ln2b, outp, (u16*)nullptr);
}

// Round 11
// 248.152 us; speedup vs baseline: 1.3602x; 1.0110x over previous
//
#include <hip/hip_runtime.h>
#include <cstdint>
#include <cstddef>

typedef unsigned short u16;
typedef unsigned int u32;
typedef __bf16 bf16x8 __attribute__((ext_vector_type(8)));
typedef float f32x4 __attribute__((ext_vector_type(4)));

#define DEVI static __device__ __forceinline__

// round-to-nearest-even fp32 -> bf16
DEVI u16 f2bf(float f) {
  u32 u = __builtin_bit_cast(u32, f);
  u = (u + 0x7fffu + ((u >> 16) & 1u)) >> 16;
  return (u16)u;
}
DEVI float bf2f(u16 u) { return __builtin_bit_cast(float, (u32)u << 16); }

// async global->LDS, 16B per lane. LDS dest is wave-uniform base + lane*16.
DEVI void gll16(const void* gsrc, const void* ldst) {
  __builtin_amdgcn_global_load_lds(
      (const __attribute__((address_space(1))) u32*)(uintptr_t)gsrc,
      (__attribute__((address_space(3))) u32*)(u32)(uintptr_t)ldst, 16, 0, 0);
}

DEVI float wredsum(float v) {
  v += __shfl_xor(v, 32); v += __shfl_xor(v, 16); v += __shfl_xor(v, 8);
  v += __shfl_xor(v, 4);  v += __shfl_xor(v, 2);  v += __shfl_xor(v, 1);
  return v;
}

// raw s_barrier with compiler memory fences (no vmcnt drain!)
DEVI void barx() {
  asm volatile("" ::: "memory");
  __builtin_amdgcn_s_barrier();
  asm volatile("" ::: "memory");
}

// ---------------- transpose + cvt: fp32 [R][C] -> bf16 [C][R] ----------------
__global__ __launch_bounds__(256) void k_tcvt(const float* __restrict__ in, u16* __restrict__ out,
                                              int R, int C, long in_z, long out_z) {
  __shared__ float tile[32][33];
  const float* inp = in + (long)blockIdx.z * in_z;
  u16* outp = out + (long)blockIdx.z * out_z;
  int c0 = blockIdx.x * 32, r0 = blockIdx.y * 32;
  int tx = threadIdx.x & 31, ty = threadIdx.x >> 5;
#pragma unroll
  for (int i = 0; i < 4; ++i)
    tile[ty + i * 8][tx] = inp[(long)(r0 + ty + i * 8) * C + c0 + tx];
  __syncthreads();
#pragma unroll
  for (int i = 0; i < 4; ++i) {
    int cc = ty + i * 8;
    outp[(long)(c0 + cc) * R + r0 + tx] = f2bf(tile[tx][cc]);
  }
}

// ---------------- elementwise fp32 -> bf16 ----------------
__global__ __launch_bounds__(256) void k_cvt(const float* __restrict__ in, u16* __restrict__ out, int n4) {
  int i = blockIdx.x * 256 + threadIdx.x;
  if (i >= n4) return;
  float4 v = ((const float4*)in)[i];
  ushort4 o;
  o.x = f2bf(v.x); o.y = f2bf(v.y); o.z = f2bf(v.z); o.w = f2bf(v.w);
  ((ushort4*)out)[i] = o;
}

// ============ high-intensity bf16 GEMM: per-wave 128x64 (the LDS-ratio fix) ============
// C = A[M][K]*Bt[N][K]^T (+bias). Tile 256x256, BK=64, 8 waves (2M x 4N),
// per-wave 128x64 (acc[8][4] = 128 VGPR). Model (m134 ds_read_b128 ~12cyc/CU):
// per K-tile: 24 b128-reads/wave x 8 waves x 12 = 2304 cyc LDS vs 128 MFMA x
// 5 x 2 waves = 1280 cyc/SIMD -> ~55% MfmaUtil ceiling (R1-R10's 64x64 waves:
// 32 reads/64 MFMA -> ~20%, matching all measurements).
// LDS 128KB = 2 buf x {Ah0,Ah1,Bh0,Bh1} 16KB units, R3's proven coalesced
// XOR-swizzled staging (row-major 128B rows, pre-swizzled source; 0 conflicts).
// 4 phases/K-tile: Ph1{read A m0-3 + B n0-1; stage Ah0/Ah1(t+1)};
// Ph2{read B n2-3; stage Bh0/Bh1(t+1)}; Ph3{read A m4-7}; Ph4{vmcnt(0) before
// end-barrier}. A-quadrant + both B sets held in regs across phases.
// Residency: all 4 units of t+1 staged by Ph2, >=2 phases of cover, drained by
// each wave's vmcnt(0) BEFORE the joint Ph4 barrier (R5 lesson). Clobber: Ph1(t)
// stages into buf(t-1), whose last readers (Ph3(t-1)) completed before the
// Ph4(t-1) joint barrier. nk >= 2.
// Split-K via z: output at base + z*pofs. EPI: 0=f32, 1=bf16(+bias), 2=GELU->bf16
template <int EPI>
__global__ __launch_bounds__(512, 2) void k_gemmE(const u16* __restrict__ A, const u16* __restrict__ Bt,
                                                  const float* __restrict__ bias, void* __restrict__ Cout,
                                                  long pofs, int M, int N, int K, int Kc) {
  __shared__ __align__(16) u16 lds[65536];  // 128 KB
  char* Lc = (char*)&lds[0];
  const int tid = threadIdx.x;
  const int lane = tid & 63, wid = tid >> 6;
  const int wr = wid >> 2, wc = wid & 3;   // 2 M-waves x 4 N-waves
  const int g = lane >> 4, r16 = lane & 15;

  // bijective XCD swizzle (grid % 8 == 0 for all launches)
  const int gx = N >> 8, gy = M >> 8;
  const int cpx = (int)gridDim.x >> 3;
  int bb = (int)blockIdx.x;
  int id = (bb & 7) * cpx + (bb >> 3);
  const int gxy = gx * gy;
  const int bz = id / gxy;
  int rr = id - bz * gxy;
  const int by = rr / gx;
  const int bx = rr - by * gx;
  const long row0 = (long)by * 256;
  const long col0 = (long)bx * 256;
  const long kbeg = (long)bz * Kc;
  const int nk = Kc >> 6;  // BK=64 K-tiles (nk >= 2)

  const size_t KB = (size_t)K * 2;  // row stride in bytes
  const char* Ab = (const char*)A + (size_t)row0 * KB + (size_t)kbeg * 2;
  const char* Bb = (const char*)Bt + (size_t)col0 * KB + (size_t)kbeg * 2;

  // stage one 16KB unit (128 rows x 128B): 2 gll16/thread, linear LDS dest,
  // inverse-swizzled global source: src = dest ^ ((destrow&7)<<4)  [R3-proven]
#define STAGE(gb, ldsoff)                                                        \
  do {                                                                           \
    _Pragma("unroll") for (int i_ = 0; i_ < 2; ++i_) {                           \
      int dq_ = i_ * 8192 + tid * 16;                                            \
      int sq_ = dq_ ^ (((dq_ >> 7) & 7) << 4);                                   \
      gll16((gb) + (size_t)(sq_ >> 7) * KB + (sq_ & 127),                        \
            Lc + (ldsoff) + i_ * 8192 + wid * 1024);                             \
    }                                                                            \
  } while (0)

  f32x4 acc[8][4];
#pragma unroll
  for (int i = 0; i < 8; ++i)
#pragma unroll
    for (int j = 0; j < 4; ++j) acc[i][j] = {0.f, 0.f, 0.f, 0.f};

  // prologue: tile0 {Ah0,Ah1,Bh0,Bh1} -> buf0 (8 loads); full drain
  STAGE(Ab, 0);
  STAGE(Ab + 128 * KB, 16384);
  STAGE(Bb, 32768);
  STAGE(Bb + 128 * KB, 49152);
  asm volatile("s_waitcnt vmcnt(0)" ::: "memory");
  barx();

  // per-thread constant addressing (row&7 == r16&7 everywhere)
  const int swz = (r16 & 7) << 4;
  const int aru = wr * 16384;                          // A unit base (Ah0/Ah1)
  const int bru = 32768 + (wc >> 1) * 16384;           // B unit base (Bh0/Bh1)
  const int brow = ((wc & 1) * 64 + r16) * 128;        // + n*2048 within unit
  const int arow = r16 * 128;                          // + m*2048 within unit
  const int kof = g * 16;                              // + ks*128 bytes (^swz)

  for (int t = 0; t < nk; ++t) {
    const int buf = (t & 1) * 65536;
    const int obuf = 65536 - buf;
    bf16x8 aF[4][2], bF[2][2], bG[2][2];
    // ---- Ph1: read A m0-3, B n0-1; stage Ah0/Ah1(t+1); MFMA [m0-3][n0-1] ----
#pragma unroll
    for (int m = 0; m < 4; ++m)
#pragma unroll
      for (int ks = 0; ks < 2; ++ks)
        aF[m][ks] = *(const bf16x8*)(Lc + buf + aru + arow + m * 2048 + ((ks * 64 + kof) ^ swz));
#pragma unroll
    for (int n = 0; n < 2; ++n)
#pragma unroll
      for (int ks = 0; ks < 2; ++ks)
        bF[n][ks] = *(const bf16x8*)(Lc + buf + bru + brow + n * 2048 + ((ks * 64 + kof) ^ swz));
    if (t + 1 < nk) {
      STAGE(Ab + (size_t)(t + 1) * 128, obuf);
      STAGE(Ab + 128 * KB + (size_t)(t + 1) * 128, obuf + 16384);
    }
    barx();
    __builtin_amdgcn_s_setprio(1);
#pragma unroll
    for (int ks = 0; ks < 2; ++ks)
#pragma unroll
      for (int m = 0; m < 4; ++m)
#pragma unroll
        for (int n = 0; n < 2; ++n)
          acc[m][n] = __builtin_amdgcn_mfma_f32_16x16x32_bf16(aF[m][ks], bF[n][ks], acc[m][n], 0, 0, 0);
    __builtin_amdgcn_s_setprio(0);
    barx();
    // ---- Ph2: read B n2-3; stage Bh0/Bh1(t+1); MFMA [m0-3][n2-3] ----
#pragma unroll
    for (int n = 0; n < 2; ++n)
#pragma unroll
      for (int ks = 0; ks < 2; ++ks)
        bG[n][ks] = *(const bf16x8*)(Lc + buf + bru + brow + (n + 2) * 2048 + ((ks * 64 + kof) ^ swz));
    if (t + 1 < nk) {
      STAGE(Bb + (size_t)(t + 1) * 128, obuf + 32768);
      STAGE(Bb + 128 * KB + (size_t)(t + 1) * 128, obuf + 49152);
    }
    barx();
    __builtin_amdgcn_s_setprio(1);
#pragma unroll
    for (int ks = 0; ks < 2; ++ks)
#pragma unroll
      for (int m = 0; m < 4; ++m)
#pragma unroll
        for (int n = 0; n < 2; ++n)
          acc[m][n + 2] = __builtin_amdgcn_mfma_f32_16x16x32_bf16(aF[m][ks], bG[n][ks], acc[m][n + 2], 0, 0, 0);
    __builtin_amdgcn_s_setprio(0);
    barx();
    // ---- Ph3: read A m4-7 (reuse aF regs); MFMA [m4-7][n0-1] ----
#pragma unroll
    for (int m = 0; m < 4; ++m)
#pragma unroll
      for (int ks = 0; ks < 2; ++ks)
        aF[m][ks] = *(const bf16x8*)(Lc + buf + aru + arow + (m + 4) * 2048 + ((ks * 64 + kof) ^ swz));
    barx();
    __builtin_amdgcn_s_setprio(1);
#pragma unroll
    for (int ks = 0; ks < 2; ++ks)
#pragma unroll
      for (int m = 0; m < 4; ++m)
#pragma unroll
        for (int n = 0; n < 2; ++n)
          acc[m + 4][n] = __builtin_amdgcn_mfma_f32_16x16x32_bf16(aF[m][ks], bF[n][ks], acc[m + 4][n], 0, 0, 0);
    __builtin_amdgcn_s_setprio(0);
    barx();
    // ---- Ph4: MFMA [m4-7][n2-3]; drain t+1 staging; end barrier ----
    __builtin_amdgcn_s_setprio(1);
#pragma unroll
    for (int ks = 0; ks < 2; ++ks)
#pragma unroll
      for (int m = 0; m < 4; ++m)
#pragma unroll
        for (int n = 0; n < 2; ++n)
          acc[m + 4][n + 2] = __builtin_amdgcn_mfma_f32_16x16x32_bf16(aF[m][ks], bG[n][ks], acc[m + 4][n + 2], 0, 0, 0);
    __builtin_amdgcn_s_setprio(0);
    if (t + 1 < nk) asm volatile("s_waitcnt vmcnt(0)" ::: "memory");
    barx();
  }
#undef STAGE

  // epilogue: C/D mapping col=lane&15, row=(lane>>4)*4+j
  float* outf = (float*)Cout + (long)bz * pofs;
  u16* outh = (u16*)Cout + (long)bz * pofs;
#pragma unroll
  for (int n = 0; n < 4; ++n) {
    long col = col0 + wc * 64 + n * 16 + r16;
    float bv = bias ? bias[col] : 0.f;
#pragma unroll
    for (int m = 0; m < 8; ++m) {
      long rowb = row0 + wr * 128 + m * 16 + g * 4;
#pragma unroll
      for (int j = 0; j < 4; ++j) {
        float v = acc[m][n][j] + bv;
        size_t off = (size_t)(rowb + j) * N + col;
        if (EPI == 0) {
          outf[off] = v;
        } else if (EPI == 1) {
          outh[off] = f2bf(v);
        } else {
          float gl = 0.5f * v * (1.f + erff(v * 0.70710678118f));
          outh[off] = f2bf(gl);
        }
      }
    }
  }
}

// ---------------- build V^T: qkvb[token][2048+h*64+p] -> vt[(b,h)][p][s] ----------------
__global__ __launch_bounds__(256) void k_build_vt(const u16* __restrict__ qkvb, u16* __restrict__ vt) {
  __shared__ u16 tile[32][33];
  int z = blockIdx.z, b = z >> 4, h = z & 15;
  int p0 = blockIdx.x * 32, s0 = blockIdx.y * 32;
  int tx = threadIdx.x & 31, ty = threadIdx.x >> 5;
#pragma unroll
  for (int i = 0; i < 4; ++i) {
    int s = s0 + ty + i * 8;
    tile[ty + i * 8][tx] = qkvb[(size_t)(b * 512 + s) * 3072 + 2048 + h * 64 + p0 + tx];
  }
  __syncthreads();
#pragma unroll
  for (int i = 0; i < 4; ++i) {
    int p = ty + i * 8;
    vt[((size_t)z * 64 + p0 + p) * 512 + s0 + tx] = tile[tx][p];
  }
}

// ---------------- fused flash attention ----------------
__global__ __launch_bounds__(256) void k_attn(const u16* __restrict__ qkvb, const u16* __restrict__ vt,
                                              u16* __restrict__ ctxb) {
  __shared__ __align__(16) u16 Qs[64 * 64];
  __shared__ __align__(16) u16 Ks[64 * 64];
  __shared__ __align__(16) u16 Vts[64 * 64];
  __shared__ __align__(16) u16 Ps[4 * 16 * 64];
  const int tid = threadIdx.x, lane = tid & 63, wid = tid >> 6;
  const int g = lane >> 4, r16 = lane & 15;
  const int z = blockIdx.y, b = z >> 4, h = z & 15;
  const int qt = blockIdx.x;
  const float CF = 0.125f * 1.44269504089f;

#pragma unroll
  for (int it = 0; it < 2; ++it) {
    int q = it * 4096 + tid * 16;
    int row = q >> 7, colb = q & 127;
    int scol = colb ^ ((row & 7) << 4);
    gll16((const char*)qkvb + ((size_t)(b * 512 + qt * 64 + row) * 3072 + h * 64) * 2 + scol,
          (const char*)Qs + it * 4096 + wid * 1024);
  }
  __syncthreads();
  bf16x8 aq[2];
  {
    int rowl = wid * 16 + r16;
#pragma unroll
    for (int kk = 0; kk < 2; ++kk)
      aq[kk] = *(const bf16x8*)(Qs + rowl * 64 + ((kk * 32 + g * 8) ^ ((rowl & 7) << 3)));
  }

  f32x4 o[4];
#pragma unroll
  for (int pi = 0; pi < 4; ++pi) o[pi] = {0.f, 0.f, 0.f, 0.f};
  float m4[4], l4[4];
#pragma unroll
  for (int j = 0; j < 4; ++j) { m4[j] = -1e30f; l4[j] = 0.f; }

  for (int kt = 0; kt < 8; ++kt) {
#pragma unroll
    for (int it = 0; it < 2; ++it) {
      int q = it * 4096 + tid * 16;
      int row = q >> 7, colb = q & 127;
      int scol = colb ^ ((row & 7) << 4);
      gll16((const char*)qkvb + ((size_t)(b * 512 + kt * 64 + row) * 3072 + 1024 + h * 64) * 2 + scol,
            (const char*)Ks + it * 4096 + wid * 1024);
      gll16((const char*)vt + ((size_t)(z * 64 + row) * 512 + kt * 64) * 2 + scol,
            (const char*)Vts + it * 4096 + wid * 1024);
    }
    __syncthreads();

    f32x4 s[4];
#pragma unroll
    for (int nj = 0; nj < 4; ++nj) s[nj] = {0.f, 0.f, 0.f, 0.f};
#pragma unroll
    for (int kk = 0; kk < 2; ++kk) {
#pragma unroll
      for (int nj = 0; nj < 4; ++nj) {
        int rowk = nj * 16 + r16;
        bf16x8 bk = *(const bf16x8*)(Ks + rowk * 64 + ((kk * 32 + g * 8) ^ ((rowk & 7) << 3)));
        s[nj] = __builtin_amdgcn_mfma_f32_16x16x32_bf16(aq[kk], bk, s[nj], 0, 0, 0);
      }
    }

    float scale[4];
#pragma unroll
    for (int j = 0; j < 4; ++j) {
      float pm = fmaxf(fmaxf(s[0][j], s[1][j]), fmaxf(s[2][j], s[3][j]));
      pm = fmaxf(pm, __shfl_xor(pm, 1));
      pm = fmaxf(pm, __shfl_xor(pm, 2));
      pm = fmaxf(pm, __shfl_xor(pm, 4));
      pm = fmaxf(pm, __shfl_xor(pm, 8));
      float mn = fmaxf(m4[j], pm);
      scale[j] = exp2f((m4[j] - mn) * CF);
      m4[j] = mn;
      int rowp = g * 4 + j;
      u16* pbase = Ps + wid * 1024 + rowp * 64;
      int sw = (rowp & 7) << 3;
      float ps = 0.f;
#pragma unroll
      for (int nj = 0; nj < 4; ++nj) {
        float p = exp2f((s[nj][j] - mn) * CF);
        ps += p;
        pbase[(nj * 16 + r16) ^ sw] = f2bf(p);
      }
      ps += __shfl_xor(ps, 1); ps += __shfl_xor(ps, 2);
      ps += __shfl_xor(ps, 4); ps += __shfl_xor(ps, 8);
      l4[j] = l4[j] * scale[j] + ps;
    }
#pragma unroll
    for (int pi = 0; pi < 4; ++pi)
#pragma unroll
      for (int j = 0; j < 4; ++j) o[pi][j] *= scale[j];

    asm volatile("s_waitcnt lgkmcnt(0)" ::: "memory");

#pragma unroll
    for (int kk = 0; kk < 2; ++kk) {
      bf16x8 ap = *(const bf16x8*)(Ps + wid * 1024 + r16 * 64 + ((kk * 32 + g * 8) ^ ((r16 & 7) << 3)));
#pragma unroll
      for (int pi = 0; pi < 4; ++pi) {
        int rowv = pi * 16 + r16;
        bf16x8 bv = *(const bf16x8*)(Vts + rowv * 64 + ((kk * 32 + g * 8) ^ ((rowv & 7) << 3)));
        o[pi] = __builtin_amdgcn_mfma_f32_16x16x32_bf16(ap, bv, o[pi], 0, 0, 0);
      }
    }
    __syncthreads();
  }

#pragma unroll
  for (int j = 0; j < 4; ++j) {
    float inv = 1.f / l4[j];
    int token = b * 512 + qt * 64 + wid * 16 + g * 4 + j;
#pragma unroll
    for (int pi = 0; pi < 4; ++pi)
      ctxb[(size_t)token * 1024 + h * 64 + pi * 16 + r16] = f2bf(o[pi][j] * inv);
  }
}

// ---------------- fused (4 bf16 partials) + bias + residual + LayerNorm ----------------
__global__ __launch_bounds__(256) void k_ln4(const u16* __restrict__ p, long pofs,
                                             const float* __restrict__ res, const float* __restrict__ bvec,
                                             const float* __restrict__ gamma, const float* __restrict__ beta,
                                             float* __restrict__ outf, u16* __restrict__ outb) {
  __shared__ float sb[8];
  int row = blockIdx.x, t = threadIdx.x, lane = t & 63, wid = t >> 6;
  const size_t rb = (size_t)row * 1024 + t * 4;
  float4 rv = *(const float4*)(res + rb);
  float4 bb = *(const float4*)(bvec + t * 4);
  float v[4] = {rv.x + bb.x, rv.y + bb.y, rv.z + bb.z, rv.w + bb.w};
#pragma unroll
  for (int z = 0; z < 4; ++z) {
    ushort4 u = *(const ushort4*)(p + (size_t)z * pofs + rb);
    v[0] += bf2f(u.x); v[1] += bf2f(u.y); v[2] += bf2f(u.z); v[3] += bf2f(u.w);
  }
  float s = v[0] + v[1] + v[2] + v[3];
  s = wredsum(s);
  if (lane == 0) sb[wid] = s;
  __syncthreads();
  float mu = (sb[0] + sb[1] + sb[2] + sb[3]) * (1.f / 1024.f);
  float q = 0.f;
#pragma unroll
  for (int i = 0; i < 4; ++i) { float d = v[i] - mu; q += d * d; }
  q = wredsum(q);
  if (lane == 0) sb[4 + wid] = q;
  __syncthreads();
  float rstd = rsqrtf((sb[4] + sb[5] + sb[6] + sb[7]) * (1.f / 1024.f) + 1e-5f);
  float4 gv = *(const float4*)(gamma + t * 4);
  float4 bt = *(const float4*)(beta + t * 4);
  float ov[4];
  ov[0] = (v[0] - mu) * rstd * gv.x + bt.x;
  ov[1] = (v[1] - mu) * rstd * gv.y + bt.y;
  ov[2] = (v[2] - mu) * rstd * gv.z + bt.z;
  ov[3] = (v[3] - mu) * rstd * gv.w + bt.w;
  *(float4*)(outf + rb) = {ov[0], ov[1], ov[2], ov[3]};
  if (outb) {
    ushort4 ob = {f2bf(ov[0]), f2bf(ov[1]), f2bf(ov[2]), f2bf(ov[3])};
    *(ushort4*)(outb + rb) = ob;
  }
}

// ---------------- orchestration ----------------
// Workspace map (MB), time-multiplexed (R4 layout, validated R6-R10):
//   [0,6) wqkvb | [6,8) woutb | [8,16) wffn1b | [16,24) free | [24,32) xb/ctxb/r1b
//   [32,56) qkvb -> qp0..2 -> hb | [56,64) vt -> qp3 -> hb | [64,72) free
//   [72,80) wffn2b.  qp0..3 @ [32,64) stride 8MB; pp0..3 @ [0,32) stride 8MB.
//   r1 fp32 in d_out. Peak 80 MB.
extern "C" void kernel_launch(void* const* d_in, const int* in_sizes, int n_in,
                              void* d_out, int out_size, void* d_ws, size_t ws_size,
                              hipStream_t stream) {
  const float* x      = (const float*)d_in[0];
  const float* w_qkv  = (const float*)d_in[1];
  const float* b_qkv  = (const float*)d_in[2];
  const float* w_out  = (const float*)d_in[3];
  const float* b_out  = (const float*)d_in[4];
  const float* ln1s   = (const float*)d_in[5];
  const float* ln1b   = (const float*)d_in[6];
  const float* w_ffn1 = (const float*)d_in[7];
  const float* b_ffn1 = (const float*)d_in[8];
  const float* w_ffn2 = (const float*)d_in[9];
  const float* b_ffn2 = (const float*)d_in[10];
  const float* ln2s   = (const float*)d_in[11];
  const float* ln2b   = (const float*)d_in[12];

  char* ws = (char*)d_ws;
  const size_t MB = 1024 * 1024;
  u16* wqkvb   = (u16*)(ws + 0 * MB);
  u16* woutb   = (u16*)(ws + 6 * MB);
  u16* wffn1b  = (u16*)(ws + 8 * MB);
  u16* wffn2b  = (u16*)(ws + 72 * MB);
  u16* xb      = (u16*)(ws + 24 * MB);
  u16* ctxb    = xb;
  u16* r1b     = xb;
  u16* qkvb    = (u16*)(ws + 32 * MB);
  u16* vt      = (u16*)(ws + 56 * MB);
  u16* qp      = (u16*)(ws + 32 * MB);   // 4 bf16 partials, stride 8MB
  u16* hb      = (u16*)(ws + 32 * MB);
  u16* pp      = (u16*)(ws + 0 * MB);    // 4 bf16 partials, stride 8MB
  float* r1    = (float*)d_out;
  float* outp  = (float*)d_out;
  const long PSTRIDE = 4096L * 1024L;    // elements per bf16 partial (8MB)

  // pack weights (transpose to [N][K] bf16)
  k_tcvt<<<dim3(32, 32, 3), 256, 0, stream>>>(w_qkv, wqkvb, 1024, 1024, 1024 * 1024, 1024 * 1024);
  k_tcvt<<<dim3(32, 32, 1), 256, 0, stream>>>(w_out, woutb, 1024, 1024, 0, 0);
  k_tcvt<<<dim3(128, 32, 1), 256, 0, stream>>>(w_ffn1, wffn1b, 1024, 4096, 0, 0);
  k_tcvt<<<dim3(32, 128, 1), 256, 0, stream>>>(w_ffn2, wffn2b, 4096, 1024, 0, 0);
  k_cvt<<<4096, 256, 0, stream>>>(x, xb, 1048576);

  // qkv = x @ w_qkv + b_qkv  (bf16 out): grid 12x16 = 192 blocks, nk=16
  k_gemmE<1><<<dim3(12 * 16), 512, 0, stream>>>(xb, wqkvb, b_qkv, qkvb, 0, 4096, 3072, 1024, 1024);
  k_build_vt<<<dim3(2, 16, 128), 256, 0, stream>>>(qkvb, vt);
  k_attn<<<dim3(8, 128), 256, 0, stream>>>(qkvb, vt, ctxb);

  // attn_out partials = ctx @ w_out (split-K=4: 4x16x4 = 256 blocks, nk=4, bf16 partials)
  k_gemmE<1><<<dim3(4 * 16 * 4), 512, 0, stream>>>(ctxb, woutb, nullptr, qp, PSTRIDE,
                                                   4096, 1024, 1024, 256);
  // r1 = LN(x + sum(qp) + b_out) -> fp32 (d_out) + bf16
  k_ln4<<<4096, 256, 0, stream>>>(qp, PSTRIDE, x, b_out, ln1s, ln1b, r1, r1b);

  // h = gelu(r1 @ w_ffn1 + b_ffn1): grid 16x16 = 256 blocks, nk=16
  k_gemmE<2><<<dim3(16 * 16), 512, 0, stream>>>(r1b, wffn1b, b_ffn1, hb, 0, 4096, 4096, 1024, 1024);

  // ffn2 partials = h @ w_ffn2 (split-K=4: 256 blocks, nk=16, bf16 partials)
  k_gemmE<1><<<dim3(4 * 16 * 4), 512, 0, stream>>>(hb, wffn2b, nullptr, pp, PSTRIDE,
                                                   4096, 1024, 4096, 1024);
  // out = LN(r1 + sum(pp) + b_ffn2)
  k_ln4<<<4096, 256, 0, stream>>>(pp, PSTRIDE, r1, b_ffn2, ln2s, ln2b, outp, (u16*)nullptr);
}